// Round 2
// baseline (5761.492 us; speedup 1.0000x reference)
//
#include <hip/hip_runtime.h>
#include <math.h>

#define N_  6000
#define F_  16
#define S_  64
#define D_  256
#define H_  8
#define KK_ 32
#define L_  2
#define DH_ 32
#define E_  (N_*KK_ + N_)   // 198000 edges
#define NF_ (N_*F_)         // 96000 token rows
#define NC_ 1500            // VA chunk: nodes per chunk
#define NCHUNK_ (N_/NC_)    // 4 chunks
#define CR_ (NC_*F_)        // 24000 rows per chunk

// ---------------- device helpers ----------------

__device__ __forceinline__ float geluf(float x) {
  return 0.5f * x * (1.0f + erff(x * 0.7071067811865476f));
}
__device__ __forceinline__ float sigmf(float x) {
  return 1.0f / (1.0f + expf(-x));
}
__device__ __forceinline__ float block_sum_256(float v, float* red) {
  int tid = threadIdx.x;
  red[tid] = v; __syncthreads();
  #pragma unroll
  for (int s = 128; s > 0; s >>= 1) {
    if (tid < s) red[tid] += red[tid + s];
    __syncthreads();
  }
  float r = red[0];
  __syncthreads();
  return r;
}
// order-preserving float<->uint map for atomicMax on floats (any sign)
__device__ __forceinline__ unsigned fmap(float f) {
  unsigned u = __float_as_uint(f);
  return (u & 0x80000000u) ? ~u : (u | 0x80000000u);
}
__device__ __forceinline__ float funmap(unsigned u) {
  unsigned b = (u & 0x80000000u) ? (u ^ 0x80000000u) : ~u;
  return __uint_as_float(b);
}

// ---------------- GRU (fused einsum + gates) ----------------
__global__ __launch_bounds__(256)
void gru_kernel(const float* __restrict__ x, const float* __restrict__ Wih,
                const float* __restrict__ bih, const float* __restrict__ bhh,
                float* __restrict__ emb) {
  __shared__ float xs[64][33];
  __shared__ float ws[3][64][33];
  int nb = blockIdx.x * 64, kb = blockIdx.y * 64, f = blockIdx.z;
  int tid = threadIdx.x;
  int tx = tid & 15, ty = tid >> 4;
  float accR[4][4] = {}, accZ[4][4] = {}, accN[4][4] = {};
  for (int s0 = 0; s0 < S_; s0 += 32) {
    #pragma unroll
    for (int i = 0; i < 8; i++) {
      int idx = tid + i * 256;
      int n = idx >> 5, ss = idx & 31;
      int gn = nb + n;
      xs[n][ss] = (gn < N_) ? x[((size_t)gn * F_ + f) * S_ + s0 + ss] : 0.f;
    }
    #pragma unroll
    for (int g = 0; g < 3; g++)
      #pragma unroll
      for (int i = 0; i < 8; i++) {
        int idx = tid + i * 256;
        int k = idx >> 5, ss = idx & 31;
        ws[g][k][ss] = Wih[((size_t)f * 768 + g * 256 + kb + k) * S_ + s0 + ss];
      }
    __syncthreads();
    for (int ss = 0; ss < 32; ss++) {
      float a[4];
      #pragma unroll
      for (int i = 0; i < 4; i++) a[i] = xs[ty * 4 + i][ss];
      #pragma unroll
      for (int j = 0; j < 4; j++) {
        float wr = ws[0][tx * 4 + j][ss];
        float wz = ws[1][tx * 4 + j][ss];
        float wn = ws[2][tx * 4 + j][ss];
        #pragma unroll
        for (int i = 0; i < 4; i++) {
          accR[i][j] += a[i] * wr;
          accZ[i][j] += a[i] * wz;
          accN[i][j] += a[i] * wn;
        }
      }
    }
    __syncthreads();
  }
  #pragma unroll
  for (int i = 0; i < 4; i++) {
    int gn = nb + ty * 4 + i;
    if (gn >= N_) continue;
    #pragma unroll
    for (int j = 0; j < 4; j++) {
      int k = kb + tx * 4 + j;
      float r  = sigmf(accR[i][j] + bih[f * 768 + k]       + bhh[f * 768 + k]);
      float z  = sigmf(accZ[i][j] + bih[f * 768 + 256 + k] + bhh[f * 768 + 256 + k]);
      float ng = tanhf(accN[i][j] + bih[f * 768 + 512 + k] + r * bhh[f * 768 + 512 + k]);
      emb[((size_t)gn * F_ + f) * D_ + k] = (1.f - z) * ng;
    }
  }
}

// ---------------- generic tiled SGEMM ----------------
#define LDP 68
template <int EPI>  // 0 = none, 1 = gelu
__global__ __launch_bounds__(256)
void gemm_nn(const float* __restrict__ A, const float* __restrict__ B,
             const float* __restrict__ bias, float* __restrict__ C,
             int M, int K, int Nc) {
  __shared__ __align__(16) float as[16][LDP];
  __shared__ __align__(16) float bs[16][LDP];
  int mb = blockIdx.y * 64, nb = blockIdx.x * 64;
  int tid = threadIdx.x;
  int tx = tid & 15, ty = tid >> 4;
  float acc[4][4] = {};
  for (int k0 = 0; k0 < K; k0 += 16) {
    #pragma unroll
    for (int i = 0; i < 4; i++) {
      int idx = tid + i * 256;
      int m = idx >> 4, kk = idx & 15;
      int gm = mb + m;
      as[kk][m] = (gm < M) ? A[(size_t)gm * K + k0 + kk] : 0.f;
    }
    #pragma unroll
    for (int i = 0; i < 4; i++) {
      int idx = tid + i * 256;
      int kk = idx >> 6, n = idx & 63;
      int gn = nb + n;
      bs[kk][n] = (gn < Nc) ? B[(size_t)(k0 + kk) * Nc + gn] : 0.f;
    }
    __syncthreads();
    #pragma unroll
    for (int kk = 0; kk < 16; kk++) {
      float a[4], b[4];
      #pragma unroll
      for (int i = 0; i < 4; i++) a[i] = as[kk][ty * 4 + i];
      #pragma unroll
      for (int j = 0; j < 4; j++) b[j] = bs[kk][tx * 4 + j];
      #pragma unroll
      for (int i = 0; i < 4; i++)
        #pragma unroll
        for (int j = 0; j < 4; j++) acc[i][j] += a[i] * b[j];
    }
    __syncthreads();
  }
  #pragma unroll
  for (int i = 0; i < 4; i++) {
    int gm = mb + ty * 4 + i;
    if (gm >= M) continue;
    #pragma unroll
    for (int j = 0; j < 4; j++) {
      int gn = nb + tx * 4 + j;
      if (gn >= Nc) continue;
      float c = acc[i][j] + (bias ? bias[gn] : 0.f);
      if (EPI == 1) c = geluf(c);
      C[(size_t)gm * Nc + gn] = c;
    }
  }
}

// C[M,Nc] = A[M,K] * B[Nc,K]^T
__global__ __launch_bounds__(256)
void gemm_nt(const float* __restrict__ A, const float* __restrict__ B,
             float* __restrict__ C, int M, int K, int Nc) {
  __shared__ __align__(16) float as[16][LDP];
  __shared__ __align__(16) float bs[16][LDP];
  int mb = blockIdx.y * 64, nb = blockIdx.x * 64;
  int tid = threadIdx.x;
  int tx = tid & 15, ty = tid >> 4;
  float acc[4][4] = {};
  for (int k0 = 0; k0 < K; k0 += 16) {
    #pragma unroll
    for (int i = 0; i < 4; i++) {
      int idx = tid + i * 256;
      int m = idx >> 4, kk = idx & 15;
      int gm = mb + m;
      as[kk][m] = (gm < M) ? A[(size_t)gm * K + k0 + kk] : 0.f;
    }
    #pragma unroll
    for (int i = 0; i < 4; i++) {
      int idx = tid + i * 256;
      int n = idx >> 4, kk = idx & 15;
      int gn = nb + n;
      bs[kk][n] = (gn < Nc) ? B[(size_t)gn * K + k0 + kk] : 0.f;
    }
    __syncthreads();
    #pragma unroll
    for (int kk = 0; kk < 16; kk++) {
      float a[4], b[4];
      #pragma unroll
      for (int i = 0; i < 4; i++) a[i] = as[kk][ty * 4 + i];
      #pragma unroll
      for (int j = 0; j < 4; j++) b[j] = bs[kk][tx * 4 + j];
      #pragma unroll
      for (int i = 0; i < 4; i++)
        #pragma unroll
        for (int j = 0; j < 4; j++) acc[i][j] += a[i] * b[j];
    }
    __syncthreads();
  }
  #pragma unroll
  for (int i = 0; i < 4; i++) {
    int gm = mb + ty * 4 + i;
    if (gm >= M) continue;
    #pragma unroll
    for (int j = 0; j < 4; j++) {
      int gn = nb + tx * 4 + j;
      if (gn >= Nc) continue;
      C[(size_t)gm * Nc + gn] = acc[i][j];
    }
  }
}

// ---------------- LayerNorm variants (D=256, one block per row) ----------------
__global__ __launch_bounds__(256)
void ln_kernel(const float* __restrict__ in, const float* __restrict__ g,
               const float* __restrict__ b, float* __restrict__ out) {
  __shared__ float red[256];
  size_t row = blockIdx.x;
  int tid = threadIdx.x;
  float v = in[row * 256 + tid];
  float mean = block_sum_256(v, red) * (1.f / 256.f);
  float d = v - mean;
  float var = block_sum_256(d * d, red) * (1.f / 256.f);
  out[row * 256 + tid] = d * rsqrtf(var + 1e-5f) * g[tid] + b[tid];
}

// emb = LN(gelu(o) + emb)
__global__ __launch_bounds__(256)
void resid_gelu_ln_kernel(const float* __restrict__ o, float* __restrict__ emb,
                          const float* __restrict__ g, const float* __restrict__ b) {
  __shared__ float red[256];
  size_t row = blockIdx.x;
  int tid = threadIdx.x;
  float v = geluf(o[row * 256 + tid]) + emb[row * 256 + tid];
  float mean = block_sum_256(v, red) * (1.f / 256.f);
  float d = v - mean;
  float var = block_sum_256(d * d, red) * (1.f / 256.f);
  emb[row * 256 + tid] = d * rsqrtf(var + 1e-5f) * g[tid] + b[tid];
}

// ---------------- per-node attention over F=16 tokens ----------------
__global__ __launch_bounds__(128)
void attn_kernel(float* __restrict__ q, const float* __restrict__ k,
                 const float* __restrict__ v) {
  __shared__ float qs[16][260];
  __shared__ float ks[16][260];
  __shared__ float vs[16][260];
  int n = blockIdx.x, tid = threadIdx.x;
  size_t base = (size_t)n * (F_ * D_);
  for (int i = tid; i < F_ * D_; i += 128) {
    int r = i >> 8, cc = i & 255;
    qs[r][cc] = q[base + i];
    ks[r][cc] = k[base + i];
    vs[r][cc] = v[base + i];
  }
  __syncthreads();
  int c = tid & 15, h = tid >> 4;   // c: query token, h: head
  const float scale = 0.17677669529663687f;  // 1/sqrt(32)
  float sc[16];
  float mx = -3e38f;
  #pragma unroll
  for (int s = 0; s < 16; s++) {
    float acc = 0.f;
    #pragma unroll
    for (int e = 0; e < 32; e++)
      acc += qs[c][h * 32 + e] * ks[s][h * 32 + e];
    sc[s] = acc * scale;
    mx = fmaxf(mx, sc[s]);
  }
  float sum = 0.f;
  #pragma unroll
  for (int s = 0; s < 16; s++) { sc[s] = expf(sc[s] - mx); sum += sc[s]; }
  float inv = 1.f / sum;
  #pragma unroll
  for (int d = 0; d < 32; d++) {
    float acc = 0.f;
    #pragma unroll
    for (int s = 0; s < 16; s++) acc += sc[s] * vs[s][h * 32 + d];
    q[base + (size_t)c * 256 + h * 32 + d] = acc * inv;
  }
}

// ---------------- feature importance ----------------
__global__ __launch_bounds__(256)
void rowdot_kernel(const float* __restrict__ A, const float* __restrict__ w,
                   const float* __restrict__ bscalar, float* __restrict__ out, int K) {
  __shared__ float red[256];
  int row = blockIdx.x, tid = threadIdx.x;
  float acc = 0.f;
  for (int d = tid; d < K; d += 256) acc += A[(size_t)row * K + d] * w[d];
  float s = block_sum_256(acc, red);
  if (tid == 0) out[row] = s + bscalar[0];
}

__global__ void fi_softmax_kernel(const float* __restrict__ w, float* __restrict__ fi) {
  int n = blockIdx.x * 256 + threadIdx.x;
  if (n >= N_) return;
  float mx = -3e38f;
  for (int f = 0; f < 16; f++) mx = fmaxf(mx, w[n * 16 + f]);
  float e[16], s = 0.f;
  for (int f = 0; f < 16; f++) { e[f] = expf(w[n * 16 + f] - mx); s += e[f]; }
  float inv = 1.f / s;
  for (int f = 0; f < 16; f++) fi[n * 16 + f] = e[f] * inv;
}

__global__ __launch_bounds__(256)
void node_kernel(const float* __restrict__ fi, const float* __restrict__ emb,
                 float* __restrict__ node) {
  int n = blockIdx.x, d = threadIdx.x;
  float acc = 0.f;
  for (int f = 0; f < 16; f++)
    acc += fi[n * 16 + f] * emb[((size_t)n * 16 + f) * 256 + d];
  node[(size_t)n * 256 + d] = acc;
}

__global__ __launch_bounds__(256)
void l2norm_kernel(const float* __restrict__ in, float* __restrict__ out) {
  __shared__ float red[256];
  size_t row = blockIdx.x;
  int tid = threadIdx.x;
  float v = in[row * 256 + tid];
  float ss = block_sum_256(v * v, red);
  out[row * 256 + tid] = v * rsqrtf(ss + 1e-12f);
}

// ---------------- top-k / bottom-k selection ----------------
__global__ __launch_bounds__(256)
void topk_kernel(const float* __restrict__ sim, int* __restrict__ top,
                 int* __restrict__ bot) {
  __shared__ float srow[N_];
  __shared__ float rv[256];
  __shared__ int ri[256];
  int i = blockIdx.x, tid = threadIdx.x;
  for (int pass = 0; pass < 2; pass++) {
    for (int j = tid; j < N_; j += 256) {
      float v = sim[(size_t)i * N_ + j];
      srow[j] = pass == 0 ? v : -v;
    }
    __syncthreads();
    if (tid == 0) srow[i] = -1e9f;
    __syncthreads();
    int* dst = pass == 0 ? top : bot;
    for (int t = 0; t < KK_; t++) {
      float bv = -3e38f; int bi = N_;
      for (int j = tid; j < N_; j += 256) {
        float v = srow[j];
        if (v > bv || (v == bv && j < bi)) { bv = v; bi = j; }
      }
      rv[tid] = bv; ri[tid] = bi;
      __syncthreads();
      for (int s = 128; s > 0; s >>= 1) {
        if (tid < s) {
          if (rv[tid + s] > rv[tid] || (rv[tid + s] == rv[tid] && ri[tid + s] < ri[tid])) {
            rv[tid] = rv[tid + s]; ri[tid] = ri[tid + s];
          }
        }
        __syncthreads();
      }
      if (tid == 0) { dst[i * KK_ + t] = ri[0]; srow[ri[0]] = -1e9f; }
      __syncthreads();
    }
  }
}

// ---------------- GAT ----------------
__global__ void gat_esed_kernel(const float* __restrict__ h, const float* __restrict__ asrc,
                                const float* __restrict__ adst,
                                float* __restrict__ es, float* __restrict__ ed) {
  int idx = blockIdx.x * 256 + threadIdx.x;
  if (idx >= N_ * H_) return;
  int hh = idx & 7;
  const float* hp = h + (size_t)(idx >> 3) * 256 + hh * 32;
  float a = 0.f, b = 0.f;
  for (int d = 0; d < 32; d++) {
    float hv = hp[d];
    a += hv * asrc[hh * 32 + d];
    b += hv * adst[hh * 32 + d];
  }
  es[idx] = a; ed[idx] = b;
}

__global__ void gat_init_kernel(unsigned* __restrict__ m_u, float* __restrict__ sbuf,
                                float* __restrict__ out) {
  int idx = blockIdx.x * 256 + threadIdx.x;
  if (idx < N_ * H_) { m_u[idx] = fmap(-1e9f); sbuf[idx] = 0.f; }
  if (idx < N_ * D_) out[idx] = 0.f;
}

__device__ __forceinline__ void edge_decode(int e, const int* nbr, int& src, int& tgt, bool& valid) {
  if (e < N_ * KK_) { src = e / KK_; tgt = nbr[e]; valid = (src != tgt); }
  else { src = tgt = e - N_ * KK_; valid = true; }
}

__global__ void gat_edge_max_kernel(const int* __restrict__ nbr, const float* __restrict__ es,
                                    const float* __restrict__ ed, unsigned* __restrict__ m_u) {
  int t = blockIdx.x * 256 + threadIdx.x;
  if (t >= E_ * H_) return;
  int e = t >> 3, hh = t & 7;
  int src, tgt; bool valid;
  edge_decode(e, nbr, src, tgt, valid);
  float ev = -1e9f;
  if (valid) {
    float xv = es[src * H_ + hh] + ed[tgt * H_ + hh];
    ev = xv > 0.f ? xv : 0.2f * xv;
  }
  atomicMax(&m_u[tgt * H_ + hh], fmap(ev));
}

__global__ void gat_edge_sum_kernel(const int* __restrict__ nbr, const float* __restrict__ es,
                                    const float* __restrict__ ed, const unsigned* __restrict__ m_u,
                                    float* __restrict__ sbuf, float* __restrict__ p) {
  int t = blockIdx.x * 256 + threadIdx.x;
  if (t >= E_ * H_) return;
  int e = t >> 3, hh = t & 7;
  int src, tgt; bool valid;
  edge_decode(e, nbr, src, tgt, valid);
  float pv = 0.f;
  if (valid) {
    float xv = es[src * H_ + hh] + ed[tgt * H_ + hh];
    float ev = xv > 0.f ? xv : 0.2f * xv;
    pv = expf(ev - funmap(m_u[tgt * H_ + hh]));
  }
  p[t] = pv;
  if (pv != 0.f) atomicAdd(&sbuf[tgt * H_ + hh], pv);
}

__global__ __launch_bounds__(256)
void gat_agg_kernel(const int* __restrict__ nbr, const float* __restrict__ p,
                    const float* __restrict__ sbuf, const float* __restrict__ h,
                    float* __restrict__ out) {
  long long t = (long long)blockIdx.x * 256 + threadIdx.x;
  if (t >= (long long)E_ * 256) return;
  int e = (int)(t >> 8), d = (int)(t & 255), hh = d >> 5;
  int src, tgt; bool valid;
  edge_decode(e, nbr, src, tgt, valid);
  float pv = p[e * H_ + hh];
  if (pv == 0.f) return;
  float alpha = pv / (sbuf[tgt * H_ + hh] + 1e-16f);
  atomicAdd(&out[(size_t)tgt * 256 + d], alpha * h[(size_t)src * 256 + d]);
}

__global__ void add_bias_kernel(float* __restrict__ out, const float* __restrict__ bias) {
  int idx = blockIdx.x * 256 + threadIdx.x;
  if (idx < N_ * D_) out[idx] += bias[idx & 255];
}

// ---------------- gating fuse + double LN ----------------
__global__ __launch_bounds__(256)
void fuse_kernel(const float* __restrict__ so, const float* __restrict__ to,
                 const float* __restrict__ bo, const float* __restrict__ impW,
                 const float* __restrict__ impb, const float* __restrict__ node,
                 const float* __restrict__ gag, const float* __restrict__ gab,
                 const float* __restrict__ fing, const float* __restrict__ finb,
                 float* __restrict__ outv) {
  __shared__ float red[256];
  size_t row = blockIdx.x;
  int tid = threadIdx.x;
  float s0 = so[row * 256 + tid];
  float t0 = to[row * 256 + tid];
  float b0 = bo[row * 256 + tid];
  float l0 = block_sum_256(s0 * impW[tid], red) + impb[0];
  float l1 = block_sum_256(t0 * impW[256 + tid], red) + impb[1];
  float l2 = block_sum_256(b0 * impW[512 + tid], red) + impb[2];
  float mx = fmaxf(l0, fmaxf(l1, l2));
  float e0 = expf(l0 - mx), e1 = expf(l1 - mx), e2 = expf(l2 - mx);
  float inv = 1.f / (e0 + e1 + e2);
  float fused = (e0 * s0 + e1 * t0 + e2 * b0) * inv;
  float v = geluf(fused) + node[row * 256 + tid];
  float mean = block_sum_256(v, red) * (1.f / 256.f);
  float d = v - mean;
  float var = block_sum_256(d * d, red) * (1.f / 256.f);
  float y = d * rsqrtf(var + 1e-5f) * gag[tid] + gab[tid];
  mean = block_sum_256(y, red) * (1.f / 256.f);
  d = y - mean;
  var = block_sum_256(d * d, red) * (1.f / 256.f);
  outv[row * 256 + tid] = d * rsqrtf(var + 1e-5f) * fing[tid] + finb[tid];
}

// ---------------- host launch ----------------
// Workspace budget (floats), peak 43,008,000 fl = 172 MB:
//   emb  [0          .. 24,576,000)                       live: GRU -> node_kernel
//   qbuf [24,576,000 .. 30,720,000)  (chunk [NC,F,D])     live: VA + fi chunks
//   kbuf [30,720,000 .. 36,864,000)
//   vbuf [36,864,000 .. 43,008,000)                       <- peak high-water mark
//   sim  [0 .. 36,000,000)           overlays dead emb/q/k        (after node+xn)
//   persistent smalls overlay dead vbuf tail / gap below it:
//     wbuf 36,000,000  fibuf 36,096,000  nodeb 36,192,000  xnb 37,728,000
//     topi 39,264,000  boti 39,456,000   (end 39,648,000)
//   post-topk smalls overlay dead sim [0 .. 12,528,000):
//     so 0  to 1,536,000  bo 3,072,000  hbuf 4,608,000  esb 6,144,000
//     edb 6,192,000  mu 6,240,000  sb 6,288,000  pb 6,336,000
//     outv 7,920,000  hid 9,456,000
extern "C" void kernel_launch(void* const* d_in, const int* in_sizes, int n_in,
                              void* d_out, int out_size, void* d_ws, size_t ws_size,
                              hipStream_t stream) {
  const float* x        = (const float*)d_in[0];
  const float* gru_Wih  = (const float*)d_in[1];
  const float* gru_bih  = (const float*)d_in[2];
  const float* gru_bhh  = (const float*)d_in[3];
  const float* va_Wq    = (const float*)d_in[4];
  const float* va_bq    = (const float*)d_in[5];
  const float* va_Wk    = (const float*)d_in[6];
  const float* va_bk    = (const float*)d_in[7];
  const float* va_Wv    = (const float*)d_in[8];
  const float* va_bv    = (const float*)d_in[9];
  const float* va_lnq_g = (const float*)d_in[10];
  const float* va_lnq_b = (const float*)d_in[11];
  const float* va_lnk_g = (const float*)d_in[12];
  const float* va_lnk_b = (const float*)d_in[13];
  const float* va_lnv_g = (const float*)d_in[14];
  const float* va_lnv_b = (const float*)d_in[15];
  const float* va_Wo    = (const float*)d_in[16];
  const float* va_bo    = (const float*)d_in[17];
  const float* va_ln_g  = (const float*)d_in[18];
  const float* va_ln_b  = (const float*)d_in[19];
  const float* va_fi_W1 = (const float*)d_in[20];
  const float* va_fi_b1 = (const float*)d_in[21];
  const float* va_fi_W2 = (const float*)d_in[22];
  const float* va_fi_b2 = (const float*)d_in[23];
  const float* gat_W    = (const float*)d_in[24];
  const float* gat_asrc = (const float*)d_in[25];
  const float* gat_adst = (const float*)d_in[26];
  const float* gat_bias = (const float*)d_in[27];
  const float* imp_W    = (const float*)d_in[28];
  const float* imp_b    = (const float*)d_in[29];
  const float* ga_ln_g  = (const float*)d_in[30];
  const float* ga_ln_b  = (const float*)d_in[31];
  const float* fin_ln_g = (const float*)d_in[32];
  const float* fin_ln_b = (const float*)d_in[33];
  const float* pred_W1  = (const float*)d_in[34];
  const float* pred_b1  = (const float*)d_in[35];
  const float* pred_W2  = (const float*)d_in[36];
  const float* pred_b2  = (const float*)d_in[37];

  float* base  = (float*)d_ws;
  float* emb   = base;
  float* qbuf  = base + 24576000;
  float* kbuf  = base + 30720000;
  float* vbuf  = base + 36864000;
  float* simb  = base;                        // overlays emb/q/k (dead)
  float* wbuf  = base + 36000000;
  float* fibuf = base + 36096000;
  float* nodeb = base + 36192000;
  float* xnb   = base + 37728000;
  int*   topi  = (int*)(base + 39264000);
  int*   boti  = (int*)(base + 39456000);
  // post-topk (overlay dead sim):
  float* so    = base + 0;
  float* to    = base + 1536000;
  float* bo    = base + 3072000;
  float* hbuf  = base + 4608000;
  float* esb   = base + 6144000;
  float* edb   = base + 6192000;
  unsigned* mu = (unsigned*)(base + 6240000);
  float* sb    = base + 6288000;
  float* pb    = base + 6336000;
  float* outv  = base + 7920000;
  float* hid   = base + 9456000;

  // --- TimeMixing GRU
  gru_kernel<<<dim3(94, 4, 16), 256, 0, stream>>>(x, gru_Wih, gru_bih, gru_bhh, emb);

  // --- Variable attention layers (node-chunked to bound scratch)
  for (int l = 0; l < L_; l++) {
    const float* Wq = va_Wq + (size_t)l * 65536;
    const float* Wk = va_Wk + (size_t)l * 65536;
    const float* Wv = va_Wv + (size_t)l * 65536;
    const float* Wo = va_Wo + (size_t)l * 65536;
    for (int c = 0; c < NCHUNK_; c++) {
      float* embc = emb + (size_t)c * NC_ * F_ * D_;
      gemm_nn<0><<<dim3(4, CR_/64), 256, 0, stream>>>(embc, Wq, va_bq + l * 256, qbuf, CR_, 256, 256);
      ln_kernel<<<CR_, 256, 0, stream>>>(qbuf, va_lnq_g + l * 256, va_lnq_b + l * 256, qbuf);
      gemm_nn<0><<<dim3(4, CR_/64), 256, 0, stream>>>(embc, Wk, va_bk + l * 256, kbuf, CR_, 256, 256);
      ln_kernel<<<CR_, 256, 0, stream>>>(kbuf, va_lnk_g + l * 256, va_lnk_b + l * 256, kbuf);
      gemm_nn<0><<<dim3(4, CR_/64), 256, 0, stream>>>(embc, Wv, va_bv + l * 256, vbuf, CR_, 256, 256);
      ln_kernel<<<CR_, 256, 0, stream>>>(vbuf, va_lnv_g + l * 256, va_lnv_b + l * 256, vbuf);
      attn_kernel<<<NC_, 128, 0, stream>>>(qbuf, kbuf, vbuf);
      gemm_nn<0><<<dim3(4, CR_/64), 256, 0, stream>>>(qbuf, Wo, va_bo + l * 256, kbuf, CR_, 256, 256);
      resid_gelu_ln_kernel<<<CR_, 256, 0, stream>>>(kbuf, embc, va_ln_g + l * 256, va_ln_b + l * 256);
    }
  }

  // --- feature importance (last layer's fi)
  for (int c = 0; c < NCHUNK_; c++) {
    float* embc = emb + (size_t)c * NC_ * F_ * D_;
    gemm_nn<1><<<dim3(4, CR_/64), 256, 0, stream>>>(embc, va_fi_W1 + (size_t)(L_ - 1) * 65536,
                                                    va_fi_b1 + (L_ - 1) * 256, qbuf, CR_, 256, 256);
    rowdot_kernel<<<CR_, 256, 0, stream>>>(qbuf, va_fi_W2 + (L_ - 1) * 256, va_fi_b2 + (L_ - 1),
                                           wbuf + (size_t)c * CR_, 256);
  }
  fi_softmax_kernel<<<(N_ + 255) / 256, 256, 0, stream>>>(wbuf, fibuf);
  node_kernel<<<N_, 256, 0, stream>>>(fibuf, emb, nodeb);

  // --- cosine similarity + top/bottom-k
  l2norm_kernel<<<N_, 256, 0, stream>>>(nodeb, xnb);
  gemm_nt<<<dim3(94, 94), 256, 0, stream>>>(xnb, xnb, simb, N_, 256, N_);
  topk_kernel<<<N_, 256, 0, stream>>>(simb, topi, boti);

  // --- self branch (pure linear)
  gemm_nn<0><<<dim3(4, 94), 256, 0, stream>>>(nodeb, gat_W, gat_bias, so, N_, 256, 256);

  // --- top GAT
  gemm_nn<0><<<dim3(4, 94), 256, 0, stream>>>(nodeb, gat_W + 65536, nullptr, hbuf, N_, 256, 256);
  gat_esed_kernel<<<(N_ * H_ + 255) / 256, 256, 0, stream>>>(hbuf, gat_asrc + 256, gat_adst + 256, esb, edb);
  gat_init_kernel<<<N_, 256, 0, stream>>>(mu, sb, to);
  gat_edge_max_kernel<<<(E_ * H_ + 255) / 256, 256, 0, stream>>>(topi, esb, edb, mu);
  gat_edge_sum_kernel<<<(E_ * H_ + 255) / 256, 256, 0, stream>>>(topi, esb, edb, mu, sb, pb);
  gat_agg_kernel<<<E_, 256, 0, stream>>>(topi, pb, sb, hbuf, to);
  add_bias_kernel<<<(N_ * D_ + 255) / 256, 256, 0, stream>>>(to, gat_bias + 256);

  // --- bottom GAT
  gemm_nn<0><<<dim3(4, 94), 256, 0, stream>>>(nodeb, gat_W + 2 * 65536, nullptr, hbuf, N_, 256, 256);
  gat_esed_kernel<<<(N_ * H_ + 255) / 256, 256, 0, stream>>>(hbuf, gat_asrc + 512, gat_adst + 512, esb, edb);
  gat_init_kernel<<<N_, 256, 0, stream>>>(mu, sb, bo);
  gat_edge_max_kernel<<<(E_ * H_ + 255) / 256, 256, 0, stream>>>(boti, esb, edb, mu);
  gat_edge_sum_kernel<<<(E_ * H_ + 255) / 256, 256, 0, stream>>>(boti, esb, edb, mu, sb, pb);
  gat_agg_kernel<<<E_, 256, 0, stream>>>(boti, pb, sb, hbuf, bo);
  add_bias_kernel<<<(N_ * D_ + 255) / 256, 256, 0, stream>>>(bo, gat_bias + 512);

  // --- gating fuse + double LN
  fuse_kernel<<<N_, 256, 0, stream>>>(so, to, bo, imp_W, imp_b, nodeb,
                                      ga_ln_g, ga_ln_b, fin_ln_g, fin_ln_b, outv);

  // --- predictor
  gemm_nn<1><<<dim3(8, 94), 256, 0, stream>>>(outv, pred_W1, pred_b1, hid, N_, 256, 512);
  rowdot_kernel<<<N_, 256, 0, stream>>>(hid, pred_W2, pred_b2, (float*)d_out, 512);
}

// Round 3
// 3947.628 us; speedup vs baseline: 1.4595x; 1.4595x over previous
//
#include <hip/hip_runtime.h>
#include <hip/hip_bf16.h>
#include <math.h>

#define N_  6000
#define F_  16
#define S_  64
#define D_  256
#define H_  8
#define KK_ 32
#define L_  2
#define DH_ 32
#define E_  (N_*KK_ + N_)   // 198000 edges
#define NF_ (N_*F_)         // 96000 token rows
#define NC_ 750             // VA chunk: nodes per chunk
#define NCHUNK_ (N_/NC_)    // 8 chunks
#define CR_ (NC_*F_)        // 12000 rows per chunk

typedef float f32x4 __attribute__((ext_vector_type(4)));
typedef float f32v4 __attribute__((ext_vector_type(4)));
typedef __bf16 bf16_t;
typedef bf16_t bf16x8 __attribute__((ext_vector_type(8)));

// ---------------- device helpers ----------------

__device__ __forceinline__ float geluf(float x) {
  return 0.5f * x * (1.0f + erff(x * 0.7071067811865476f));
}
__device__ __forceinline__ float sigmf(float x) {
  return 1.0f / (1.0f + expf(-x));
}
__device__ __forceinline__ float block_sum_256(float v, float* red) {
  int tid = threadIdx.x;
  red[tid] = v; __syncthreads();
  #pragma unroll
  for (int s = 128; s > 0; s >>= 1) {
    if (tid < s) red[tid] += red[tid + s];
    __syncthreads();
  }
  float r = red[0];
  __syncthreads();
  return r;
}
// order-preserving float<->uint map (larger float => larger uint)
__device__ __forceinline__ unsigned fmap(float f) {
  unsigned u = __float_as_uint(f);
  return (u & 0x80000000u) ? ~u : (u | 0x80000000u);
}
__device__ __forceinline__ float funmap(unsigned u) {
  unsigned b = (u & 0x80000000u) ? (u ^ 0x80000000u) : ~u;
  return __uint_as_float(b);
}

// ---------------- weight prep: transpose fp32 [256,OUT] -> [OUT,256] ----------------
__global__ void transpose_kernel(const float* __restrict__ src, float* __restrict__ dst, int OUT) {
  int o = blockIdx.x, i = threadIdx.x;
  dst[(size_t)o * 256 + i] = src[(size_t)i * OUT + o];
}
// concat q/k/v biases into [L][768]
__global__ void biascat_kernel(const float* __restrict__ bq, const float* __restrict__ bk,
                               const float* __restrict__ bv, float* __restrict__ dst) {
  int s = blockIdx.x, l = blockIdx.y, t = threadIdx.x;
  const float* p = (s == 0) ? bq : (s == 1) ? bk : bv;
  dst[l * 768 + s * 256 + t] = p[l * 256 + t];
}

// ---------------- GRU (fused einsum + gates, fp32) ----------------
__global__ __launch_bounds__(256)
void gru_kernel(const float* __restrict__ x, const float* __restrict__ Wih,
                const float* __restrict__ bih, const float* __restrict__ bhh,
                float* __restrict__ emb) {
  __shared__ float xs[64][33];
  __shared__ float ws[3][64][33];
  int nb = blockIdx.x * 64, kb = blockIdx.y * 64, f = blockIdx.z;
  int tid = threadIdx.x;
  int tx = tid & 15, ty = tid >> 4;
  float accR[4][4] = {}, accZ[4][4] = {}, accN[4][4] = {};
  for (int s0 = 0; s0 < S_; s0 += 32) {
    #pragma unroll
    for (int i = 0; i < 8; i++) {
      int idx = tid + i * 256;
      int n = idx >> 5, ss = idx & 31;
      int gn = nb + n;
      xs[n][ss] = (gn < N_) ? x[((size_t)gn * F_ + f) * S_ + s0 + ss] : 0.f;
    }
    #pragma unroll
    for (int g = 0; g < 3; g++)
      #pragma unroll
      for (int i = 0; i < 8; i++) {
        int idx = tid + i * 256;
        int k = idx >> 5, ss = idx & 31;
        ws[g][k][ss] = Wih[((size_t)f * 768 + g * 256 + kb + k) * S_ + s0 + ss];
      }
    __syncthreads();
    for (int ss = 0; ss < 32; ss++) {
      float a[4];
      #pragma unroll
      for (int i = 0; i < 4; i++) a[i] = xs[ty * 4 + i][ss];
      #pragma unroll
      for (int j = 0; j < 4; j++) {
        float wr = ws[0][tx * 4 + j][ss];
        float wz = ws[1][tx * 4 + j][ss];
        float wn = ws[2][tx * 4 + j][ss];
        #pragma unroll
        for (int i = 0; i < 4; i++) {
          accR[i][j] += a[i] * wr;
          accZ[i][j] += a[i] * wz;
          accN[i][j] += a[i] * wn;
        }
      }
    }
    __syncthreads();
  }
  #pragma unroll
  for (int i = 0; i < 4; i++) {
    int gn = nb + ty * 4 + i;
    if (gn >= N_) continue;
    #pragma unroll
    for (int j = 0; j < 4; j++) {
      int k = kb + tx * 4 + j;
      float r  = sigmf(accR[i][j] + bih[f * 768 + k]       + bhh[f * 768 + k]);
      float z  = sigmf(accZ[i][j] + bih[f * 768 + 256 + k] + bhh[f * 768 + 256 + k]);
      float ng = tanhf(accN[i][j] + bih[f * 768 + 512 + k] + r * bhh[f * 768 + 512 + k]);
      emb[((size_t)gn * F_ + f) * D_ + k] = (1.f - z) * ng;
    }
  }
}

// ---------------- bf16 MFMA GEMM ----------------
// C[M,Nt] = A[M,K](fp32, cvt->bf16) * Bt[Nt,K](fp32, cvt->bf16)^T  (+bias, optional gelu)
// 128x128 tile, BK=32, 4 waves (2x2), 16x16x32 MFMA, fp32 accum.
template <int EPI>
__global__ __launch_bounds__(256)
void gemm_bt_bf16(const float* __restrict__ A, const float* __restrict__ Bt,
                  const float* __restrict__ bias, float* __restrict__ C,
                  int M, int K, int Nt) {
  __shared__ __align__(16) __hip_bfloat16 As[128 * 32];
  __shared__ __align__(16) __hip_bfloat16 Bs[128 * 32];
  int mb = blockIdx.y * 128, nb = blockIdx.x * 128;
  int tid = threadIdx.x;
  int lane = tid & 63, wid = tid >> 6;
  int wm = (wid >> 1) * 64, wn = (wid & 1) * 64;
  int q = lane >> 4, m16 = lane & 15;
  int arow = tid >> 1;            // 0..127
  int acol = (tid & 1) * 16;      // k offset 0 or 16

  f32x4 acc[4][4];
  #pragma unroll
  for (int i = 0; i < 4; i++)
    #pragma unroll
    for (int j = 0; j < 4; j++) acc[i][j] = (f32x4){0.f, 0.f, 0.f, 0.f};

  for (int k0 = 0; k0 < K; k0 += 32) {
    // stage A (fp32 -> bf16)
    {
      bool ok = (mb + arow) < M;
      const float* src = A + (size_t)(mb + arow) * K + k0 + acol;
      union { __hip_bfloat16 h[16]; uint4 u[2]; } tmp;
      #pragma unroll
      for (int v = 0; v < 4; v++) {
        f32v4 d = ok ? *reinterpret_cast<const f32v4*>(src + v * 4) : (f32v4){0.f,0.f,0.f,0.f};
        tmp.h[v * 4 + 0] = __float2bfloat16(d.x);
        tmp.h[v * 4 + 1] = __float2bfloat16(d.y);
        tmp.h[v * 4 + 2] = __float2bfloat16(d.z);
        tmp.h[v * 4 + 3] = __float2bfloat16(d.w);
      }
      uint4* dst = reinterpret_cast<uint4*>(&As[arow * 32 + acol]);
      dst[0] = tmp.u[0]; dst[1] = tmp.u[1];
    }
    // stage Bt (fp32 -> bf16)
    {
      bool ok = (nb + arow) < Nt;
      const float* src = Bt + (size_t)(nb + arow) * K + k0 + acol;
      union { __hip_bfloat16 h[16]; uint4 u[2]; } tmp;
      #pragma unroll
      for (int v = 0; v < 4; v++) {
        f32v4 d = ok ? *reinterpret_cast<const f32v4*>(src + v * 4) : (f32v4){0.f,0.f,0.f,0.f};
        tmp.h[v * 4 + 0] = __float2bfloat16(d.x);
        tmp.h[v * 4 + 1] = __float2bfloat16(d.y);
        tmp.h[v * 4 + 2] = __float2bfloat16(d.z);
        tmp.h[v * 4 + 3] = __float2bfloat16(d.w);
      }
      uint4* dst = reinterpret_cast<uint4*>(&Bs[arow * 32 + acol]);
      dst[0] = tmp.u[0]; dst[1] = tmp.u[1];
    }
    __syncthreads();
    bf16x8 av[4], bv[4];
    #pragma unroll
    for (int mt = 0; mt < 4; mt++)
      av[mt] = *reinterpret_cast<const bf16x8*>(&As[(wm + mt * 16 + m16) * 32 + q * 8]);
    #pragma unroll
    for (int nt = 0; nt < 4; nt++)
      bv[nt] = *reinterpret_cast<const bf16x8*>(&Bs[(wn + nt * 16 + m16) * 32 + q * 8]);
    #pragma unroll
    for (int mt = 0; mt < 4; mt++)
      #pragma unroll
      for (int nt = 0; nt < 4; nt++)
        acc[mt][nt] = __builtin_amdgcn_mfma_f32_16x16x32_bf16(av[mt], bv[nt], acc[mt][nt], 0, 0, 0);
    __syncthreads();
  }
  // epilogue: D row = q*4+r (in-tile), col = m16
  #pragma unroll
  for (int mt = 0; mt < 4; mt++) {
    #pragma unroll
    for (int nt = 0; nt < 4; nt++) {
      #pragma unroll
      for (int r = 0; r < 4; r++) {
        int row = mb + wm + mt * 16 + q * 4 + r;
        int col = nb + wn + nt * 16 + m16;
        if (row < M && col < Nt) {
          float c = acc[mt][nt][r] + (bias ? bias[col] : 0.f);
          if (EPI == 1) c = geluf(c);
          C[(size_t)row * Nt + col] = c;
        }
      }
    }
  }
}

// ---------------- LN over 3 slices of [row,768] (q|k|v) ----------------
__device__ __forceinline__ void ln_slice(float* p, const float* g, const float* b, float* red) {
  int tid = threadIdx.x;
  float v = p[tid];
  float mean = block_sum_256(v, red) * (1.f / 256.f);
  float d = v - mean;
  float var = block_sum_256(d * d, red) * (1.f / 256.f);
  p[tid] = d * rsqrtf(var + 1e-5f) * g[tid] + b[tid];
}
__global__ __launch_bounds__(256)
void ln3_kernel(float* __restrict__ qkv,
                const float* __restrict__ gq, const float* __restrict__ bq,
                const float* __restrict__ gk, const float* __restrict__ bk,
                const float* __restrict__ gv, const float* __restrict__ bv) {
  __shared__ float red[256];
  float* row = qkv + (size_t)blockIdx.x * 768;
  ln_slice(row, gq, bq, red);
  ln_slice(row + 256, gk, bk, red);
  ln_slice(row + 512, gv, bv, red);
}

// emb = LN(gelu(o) + emb)
__global__ __launch_bounds__(256)
void resid_gelu_ln_kernel(const float* __restrict__ o, float* __restrict__ emb,
                          const float* __restrict__ g, const float* __restrict__ b) {
  __shared__ float red[256];
  size_t row = blockIdx.x;
  int tid = threadIdx.x;
  float v = geluf(o[row * 256 + tid]) + emb[row * 256 + tid];
  float mean = block_sum_256(v, red) * (1.f / 256.f);
  float d = v - mean;
  float var = block_sum_256(d * d, red) * (1.f / 256.f);
  emb[row * 256 + tid] = d * rsqrtf(var + 1e-5f) * g[tid] + b[tid];
}

// ---------------- per-node attention over F=16 tokens (qkv packed [row,768]) ----------------
__global__ __launch_bounds__(128)
void attn_kernel(const float* __restrict__ qkv, float* __restrict__ out) {
  __shared__ float qs[16][260];
  __shared__ float ks[16][260];
  __shared__ float vs[16][260];
  int n = blockIdx.x, tid = threadIdx.x;
  size_t base = (size_t)n * 16 * 768;
  for (int i = tid; i < 16 * 256; i += 128) {
    int r = i >> 8, cc = i & 255;
    qs[r][cc] = qkv[base + (size_t)r * 768 + cc];
    ks[r][cc] = qkv[base + (size_t)r * 768 + 256 + cc];
    vs[r][cc] = qkv[base + (size_t)r * 768 + 512 + cc];
  }
  __syncthreads();
  int c = tid & 15, h = tid >> 4;
  const float scale = 0.17677669529663687f;  // 1/sqrt(32)
  float sc[16];
  float mx = -3e38f;
  #pragma unroll
  for (int s = 0; s < 16; s++) {
    float acc = 0.f;
    #pragma unroll
    for (int e = 0; e < 32; e++)
      acc += qs[c][h * 32 + e] * ks[s][h * 32 + e];
    sc[s] = acc * scale;
    mx = fmaxf(mx, sc[s]);
  }
  float sum = 0.f;
  #pragma unroll
  for (int s = 0; s < 16; s++) { sc[s] = expf(sc[s] - mx); sum += sc[s]; }
  float inv = 1.f / sum;
  #pragma unroll
  for (int d = 0; d < 32; d++) {
    float acc = 0.f;
    #pragma unroll
    for (int s = 0; s < 16; s++) acc += sc[s] * vs[s][h * 32 + d];
    out[((size_t)n * 16 + c) * 256 + h * 32 + d] = acc * inv;
  }
}

// ---------------- feature importance ----------------
__global__ __launch_bounds__(256)
void rowdot_kernel(const float* __restrict__ A, const float* __restrict__ w,
                   const float* __restrict__ bscalar, float* __restrict__ out, int K) {
  __shared__ float red[256];
  int row = blockIdx.x, tid = threadIdx.x;
  float acc = 0.f;
  for (int d = tid; d < K; d += 256) acc += A[(size_t)row * K + d] * w[d];
  float s = block_sum_256(acc, red);
  if (tid == 0) out[row] = s + bscalar[0];
}

__global__ void fi_softmax_kernel(const float* __restrict__ w, float* __restrict__ fi) {
  int n = blockIdx.x * 256 + threadIdx.x;
  if (n >= N_) return;
  float mx = -3e38f;
  for (int f = 0; f < 16; f++) mx = fmaxf(mx, w[n * 16 + f]);
  float e[16], s = 0.f;
  for (int f = 0; f < 16; f++) { e[f] = expf(w[n * 16 + f] - mx); s += e[f]; }
  float inv = 1.f / s;
  for (int f = 0; f < 16; f++) fi[n * 16 + f] = e[f] * inv;
}

__global__ __launch_bounds__(256)
void node_kernel(const float* __restrict__ fi, const float* __restrict__ emb,
                 float* __restrict__ node) {
  int n = blockIdx.x, d = threadIdx.x;
  float acc = 0.f;
  for (int f = 0; f < 16; f++)
    acc += fi[n * 16 + f] * emb[((size_t)n * 16 + f) * 256 + d];
  node[(size_t)n * 256 + d] = acc;
}

__global__ __launch_bounds__(256)
void l2norm_kernel(const float* __restrict__ in, float* __restrict__ out) {
  __shared__ float red[256];
  size_t row = blockIdx.x;
  int tid = threadIdx.x;
  float v = in[row * 256 + tid];
  float ss = block_sum_256(v * v, red);
  out[row * 256 + tid] = v * rsqrtf(ss + 1e-12f);
}

// ---------------- top-k / bottom-k via exact radix select ----------------
__global__ __launch_bounds__(256)
void topk_kernel(const float* __restrict__ sim, int* __restrict__ top,
                 int* __restrict__ bot) {
  __shared__ unsigned su[N_];
  __shared__ unsigned sh[256];
  __shared__ unsigned suf[256];
  __shared__ unsigned s_b, s_r, s_cnt;
  int i = blockIdx.x, tid = threadIdx.x;
  for (int pass = 0; pass < 2; pass++) {
    int* dst = pass ? bot : top;
    for (int j = tid; j < N_; j += 256) {
      float v = sim[(size_t)i * N_ + j];
      if (pass) v = -v;
      su[j] = fmap(v);
    }
    __syncthreads();
    if (tid == 0) { su[i] = 0u; s_r = KK_; }  // self excluded: 0 = smallest uint
    __syncthreads();
    unsigned prefix = 0;
    for (int lvl = 0; lvl < 4; lvl++) {
      sh[tid] = 0; __syncthreads();
      for (int j = tid; j < N_; j += 256) {
        unsigned v = su[j];
        bool match = (lvl == 0) || ((v >> (32 - 8 * lvl)) == prefix);
        if (match) atomicAdd(&sh[(v >> (24 - 8 * lvl)) & 255u], 1u);
      }
      __syncthreads();
      suf[tid] = sh[tid]; __syncthreads();
      #pragma unroll
      for (int s = 1; s < 256; s <<= 1) {
        unsigned add = (tid + s < 256) ? suf[tid + s] : 0u;
        __syncthreads();
        suf[tid] += add;
        __syncthreads();
      }
      unsigned r = s_r;
      unsigned above = (tid < 255) ? suf[tid + 1] : 0u;
      __syncthreads();
      if (above < r && suf[tid] >= r) { s_b = (unsigned)tid; s_r = r - above; }
      __syncthreads();
      prefix = (prefix << 8) | s_b;
      __syncthreads();
    }
    unsigned T = prefix;
    if (tid == 0) s_cnt = 0;
    __syncthreads();
    for (int j = tid; j < N_; j += 256) {
      if (su[j] > T) {
        unsigned p = atomicAdd(&s_cnt, 1u);
        dst[i * KK_ + p] = j;
      }
    }
    __syncthreads();
    int r = (int)s_r;
    int base = KK_ - r;
    int last = -1;
    for (int t = 0; t < r; t++) {
      unsigned best = 0x7fffffffu;
      for (int j = tid; j < N_; j += 256)
        if (su[j] == T && j > last && (unsigned)j < best) best = (unsigned)j;
      suf[tid] = best; __syncthreads();
      #pragma unroll
      for (int s = 128; s > 0; s >>= 1) {
        if (tid < s) suf[tid] = min(suf[tid], suf[tid + s]);
        __syncthreads();
      }
      last = (int)suf[0];
      if (tid == 0) dst[i * KK_ + base + t] = last;
      __syncthreads();
    }
    __syncthreads();
  }
}

// ---------------- GAT ----------------
__global__ void gat_esed_kernel(const float* __restrict__ h, const float* __restrict__ asrc,
                                const float* __restrict__ adst,
                                float* __restrict__ es, float* __restrict__ ed) {
  int idx = blockIdx.x * 256 + threadIdx.x;
  if (idx >= N_ * H_) return;
  int hh = idx & 7;
  const float* hp = h + (size_t)(idx >> 3) * 256 + hh * 32;
  float a = 0.f, b = 0.f;
  for (int d = 0; d < 32; d++) {
    float hv = hp[d];
    a += hv * asrc[hh * 32 + d];
    b += hv * adst[hh * 32 + d];
  }
  es[idx] = a; ed[idx] = b;
}

__global__ void gat_init_kernel(unsigned* __restrict__ m_u, float* __restrict__ sbuf,
                                float* __restrict__ out) {
  int idx = blockIdx.x * 256 + threadIdx.x;
  if (idx < N_ * H_) { m_u[idx] = fmap(-1e9f); sbuf[idx] = 0.f; }
  if (idx < N_ * D_) out[idx] = 0.f;
}

__device__ __forceinline__ void edge_decode(int e, const int* nbr, int& src, int& tgt, bool& valid) {
  if (e < N_ * KK_) { src = e / KK_; tgt = nbr[e]; valid = (src != tgt); }
  else { src = tgt = e - N_ * KK_; valid = true; }
}

__global__ void gat_edge_max_kernel(const int* __restrict__ nbr, const float* __restrict__ es,
                                    const float* __restrict__ ed, unsigned* __restrict__ m_u) {
  int t = blockIdx.x * 256 + threadIdx.x;
  if (t >= E_ * H_) return;
  int e = t >> 3, hh = t & 7;
  int src, tgt; bool valid;
  edge_decode(e, nbr, src, tgt, valid);
  float ev = -1e9f;
  if (valid) {
    float xv = es[src * H_ + hh] + ed[tgt * H_ + hh];
    ev = xv > 0.f ? xv : 0.2f * xv;
  }
  atomicMax(&m_u[tgt * H_ + hh], fmap(ev));
}

__global__ void gat_edge_sum_kernel(const int* __restrict__ nbr, const float* __restrict__ es,
                                    const float* __restrict__ ed, const unsigned* __restrict__ m_u,
                                    float* __restrict__ sbuf, float* __restrict__ p) {
  int t = blockIdx.x * 256 + threadIdx.x;
  if (t >= E_ * H_) return;
  int e = t >> 3, hh = t & 7;
  int src, tgt; bool valid;
  edge_decode(e, nbr, src, tgt, valid);
  float pv = 0.f;
  if (valid) {
    float xv = es[src * H_ + hh] + ed[tgt * H_ + hh];
    float ev = xv > 0.f ? xv : 0.2f * xv;
    pv = expf(ev - funmap(m_u[tgt * H_ + hh]));
  }
  p[t] = pv;
  if (pv != 0.f) atomicAdd(&sbuf[tgt * H_ + hh], pv);
}

__global__ __launch_bounds__(256)
void gat_agg_kernel(const int* __restrict__ nbr, const float* __restrict__ p,
                    const float* __restrict__ sbuf, const float* __restrict__ h,
                    float* __restrict__ out) {
  long long t = (long long)blockIdx.x * 256 + threadIdx.x;
  if (t >= (long long)E_ * 256) return;
  int e = (int)(t >> 8), d = (int)(t & 255), hh = d >> 5;
  int src, tgt; bool valid;
  edge_decode(e, nbr, src, tgt, valid);
  float pv = p[e * H_ + hh];
  if (pv == 0.f) return;
  float alpha = pv / (sbuf[tgt * H_ + hh] + 1e-16f);
  atomicAdd(&out[(size_t)tgt * 256 + d], alpha * h[(size_t)src * 256 + d]);
}

__global__ void add_bias_kernel(float* __restrict__ out, const float* __restrict__ bias) {
  int idx = blockIdx.x * 256 + threadIdx.x;
  if (idx < N_ * D_) out[idx] += bias[idx & 255];
}

// ---------------- gating fuse + double LN ----------------
__global__ __launch_bounds__(256)
void fuse_kernel(const float* __restrict__ so, const float* __restrict__ to,
                 const float* __restrict__ bo, const float* __restrict__ impW,
                 const float* __restrict__ impb, const float* __restrict__ node,
                 const float* __restrict__ gag, const float* __restrict__ gab,
                 const float* __restrict__ fing, const float* __restrict__ finb,
                 float* __restrict__ outv) {
  __shared__ float red[256];
  size_t row = blockIdx.x;
  int tid = threadIdx.x;
  float s0 = so[row * 256 + tid];
  float t0 = to[row * 256 + tid];
  float b0 = bo[row * 256 + tid];
  float l0 = block_sum_256(s0 * impW[tid], red) + impb[0];
  float l1 = block_sum_256(t0 * impW[256 + tid], red) + impb[1];
  float l2 = block_sum_256(b0 * impW[512 + tid], red) + impb[2];
  float mx = fmaxf(l0, fmaxf(l1, l2));
  float e0 = expf(l0 - mx), e1 = expf(l1 - mx), e2 = expf(l2 - mx);
  float inv = 1.f / (e0 + e1 + e2);
  float fused = (e0 * s0 + e1 * t0 + e2 * b0) * inv;
  float v = geluf(fused) + node[row * 256 + tid];
  float mean = block_sum_256(v, red) * (1.f / 256.f);
  float d = v - mean;
  float var = block_sum_256(d * d, red) * (1.f / 256.f);
  float y = d * rsqrtf(var + 1e-5f) * gag[tid] + gab[tid];
  mean = block_sum_256(y, red) * (1.f / 256.f);
  d = y - mean;
  var = block_sum_256(d * d, red) * (1.f / 256.f);
  outv[row * 256 + tid] = d * rsqrtf(var + 1e-5f) * fing[tid] + finb[tid];
}

// ---------------- host launch ----------------
// Workspace (floats), peak 41,431,040 fl = 165.8 MB (< proven-safe 172 MB):
//   emb     0           .. 24,576,000   (GRU out; dead after node_kernel)
//   qkvbuf  24,576,000  .. 33,792,000   ([CR,768] chunk scratch; also Wo out [CR,256])
//   obuf    33,792,000  .. 36,864,000   (attn out / fi-gelu out, chunk scratch)
//   wbuf    36,864,000  fibuf 36,960,000  nodeb 37,056,000  xnb 38,592,000
//   topi    40,128,000  boti  40,320,000 (ints)
//   wtb     40,512,000  .. 41,431,040   (transposed fp32 weights + qkv bias cat)
//   sim     0 .. 36,000,000             (overlays emb/qkvbuf/obuf after they die)
//   post-topk (overlay dead sim): so 0; to 1,536,000; bo 3,072,000; hbuf 4,608,000;
//     esb 6,144,000; edb 6,192,000; mu 6,240,000; sb 6,288,000; pb 6,336,000;
//     outv 7,920,000; hid 9,456,000 (..12,528,000)
extern "C" void kernel_launch(void* const* d_in, const int* in_sizes, int n_in,
                              void* d_out, int out_size, void* d_ws, size_t ws_size,
                              hipStream_t stream) {
  const float* x        = (const float*)d_in[0];
  const float* gru_Wih  = (const float*)d_in[1];
  const float* gru_bih  = (const float*)d_in[2];
  const float* gru_bhh  = (const float*)d_in[3];
  const float* va_Wq    = (const float*)d_in[4];
  const float* va_bq    = (const float*)d_in[5];
  const float* va_Wk    = (const float*)d_in[6];
  const float* va_bk    = (const float*)d_in[7];
  const float* va_Wv    = (const float*)d_in[8];
  const float* va_bv    = (const float*)d_in[9];
  const float* va_lnq_g = (const float*)d_in[10];
  const float* va_lnq_b = (const float*)d_in[11];
  const float* va_lnk_g = (const float*)d_in[12];
  const float* va_lnk_b = (const float*)d_in[13];
  const float* va_lnv_g = (const float*)d_in[14];
  const float* va_lnv_b = (const float*)d_in[15];
  const float* va_Wo    = (const float*)d_in[16];
  const float* va_bo    = (const float*)d_in[17];
  const float* va_ln_g  = (const float*)d_in[18];
  const float* va_ln_b  = (const float*)d_in[19];
  const float* va_fi_W1 = (const float*)d_in[20];
  const float* va_fi_b1 = (const float*)d_in[21];
  const float* va_fi_W2 = (const float*)d_in[22];
  const float* va_fi_b2 = (const float*)d_in[23];
  const float* gat_W    = (const float*)d_in[24];
  const float* gat_asrc = (const float*)d_in[25];
  const float* gat_adst = (const float*)d_in[26];
  const float* gat_bias = (const float*)d_in[27];
  const float* imp_W    = (const float*)d_in[28];
  const float* imp_b    = (const float*)d_in[29];
  const float* ga_ln_g  = (const float*)d_in[30];
  const float* ga_ln_b  = (const float*)d_in[31];
  const float* fin_ln_g = (const float*)d_in[32];
  const float* fin_ln_b = (const float*)d_in[33];
  const float* pred_W1  = (const float*)d_in[34];
  const float* pred_b1  = (const float*)d_in[35];
  const float* pred_W2  = (const float*)d_in[36];
  const float* pred_b2  = (const float*)d_in[37];

  float* base   = (float*)d_ws;
  float* emb    = base;
  float* qkvbuf = base + 24576000;
  float* obuf   = base + 33792000;
  float* wbuf   = base + 36864000;
  float* fibuf  = base + 36960000;
  float* nodeb  = base + 37056000;
  float* xnb    = base + 38592000;
  int*   topi   = (int*)(base + 40128000);
  int*   boti   = (int*)(base + 40320000);
  float* wtb    = base + 40512000;
  float* simb   = base;
  // post-topk overlays:
  float* so     = base + 0;
  float* to     = base + 1536000;
  float* bo     = base + 3072000;
  float* hbuf   = base + 4608000;
  float* esb    = base + 6144000;
  float* edb    = base + 6192000;
  unsigned* mu  = (unsigned*)(base + 6240000);
  float* sb     = base + 6288000;
  float* pb     = base + 6336000;
  float* outv   = base + 7920000;
  float* hid    = base + 9456000;

  // wtb sub-offsets (floats)
  float* qkvt0  = wtb + 0;        // [768,256] layer 0
  float* qkvt1  = wtb + 196608;   // [768,256] layer 1
  float* wot0   = wtb + 393216;
  float* wot1   = wtb + 458752;
  float* fi1t   = wtb + 524288;
  float* gatt   = wtb + 589824;   // 3 x [256,256]
  float* pred1t = wtb + 786432;   // [512,256]
  float* qkvb   = wtb + 917504;   // [2,768]

  // --- weight prep (transpose to [out,in], concat qkv biases)
  transpose_kernel<<<256, 256, 0, stream>>>(va_Wq,           qkvt0,          256);
  transpose_kernel<<<256, 256, 0, stream>>>(va_Wk,           qkvt0 + 65536,  256);
  transpose_kernel<<<256, 256, 0, stream>>>(va_Wv,           qkvt0 + 131072, 256);
  transpose_kernel<<<256, 256, 0, stream>>>(va_Wq + 65536,   qkvt1,          256);
  transpose_kernel<<<256, 256, 0, stream>>>(va_Wk + 65536,   qkvt1 + 65536,  256);
  transpose_kernel<<<256, 256, 0, stream>>>(va_Wv + 65536,   qkvt1 + 131072, 256);
  transpose_kernel<<<256, 256, 0, stream>>>(va_Wo,           wot0,           256);
  transpose_kernel<<<256, 256, 0, stream>>>(va_Wo + 65536,   wot1,           256);
  transpose_kernel<<<256, 256, 0, stream>>>(va_fi_W1 + (L_-1)*65536, fi1t,   256);
  transpose_kernel<<<256, 256, 0, stream>>>(gat_W,           gatt,           256);
  transpose_kernel<<<256, 256, 0, stream>>>(gat_W + 65536,   gatt + 65536,   256);
  transpose_kernel<<<256, 256, 0, stream>>>(gat_W + 131072,  gatt + 131072,  256);
  transpose_kernel<<<512, 256, 0, stream>>>(pred_W1,         pred1t,         512);
  biascat_kernel<<<dim3(3, 2), 256, 0, stream>>>(va_bq, va_bk, va_bv, qkvb);

  // --- TimeMixing GRU
  gru_kernel<<<dim3(94, 4, 16), 256, 0, stream>>>(x, gru_Wih, gru_bih, gru_bhh, emb);

  // --- Variable attention layers (node-chunked; fused qkv GEMM)
  for (int l = 0; l < L_; l++) {
    const float* qkvt = l ? qkvt1 : qkvt0;
    const float* wot  = l ? wot1  : wot0;
    for (int c = 0; c < NCHUNK_; c++) {
      float* embc = emb + (size_t)c * NC_ * F_ * D_;
      gemm_bt_bf16<0><<<dim3(6, 94), 256, 0, stream>>>(embc, qkvt, qkvb + l * 768,
                                                       qkvbuf, CR_, 256, 768);
      ln3_kernel<<<CR_, 256, 0, stream>>>(qkvbuf,
                                          va_lnq_g + l * 256, va_lnq_b + l * 256,
                                          va_lnk_g + l * 256, va_lnk_b + l * 256,
                                          va_lnv_g + l * 256, va_lnv_b + l * 256);
      attn_kernel<<<NC_, 128, 0, stream>>>(qkvbuf, obuf);
      gemm_bt_bf16<0><<<dim3(2, 94), 256, 0, stream>>>(obuf, wot, va_bo + l * 256,
                                                       qkvbuf, CR_, 256, 256);
      resid_gelu_ln_kernel<<<CR_, 256, 0, stream>>>(qkvbuf, embc, va_ln_g + l * 256, va_ln_b + l * 256);
    }
  }

  // --- feature importance (last layer's fi)
  for (int c = 0; c < NCHUNK_; c++) {
    float* embc = emb + (size_t)c * NC_ * F_ * D_;
    gemm_bt_bf16<1><<<dim3(2, 94), 256, 0, stream>>>(embc, fi1t, va_fi_b1 + (L_-1) * 256,
                                                     obuf, CR_, 256, 256);
    rowdot_kernel<<<CR_, 256, 0, stream>>>(obuf, va_fi_W2 + (L_-1) * 256, va_fi_b2 + (L_-1),
                                           wbuf + (size_t)c * CR_, 256);
  }
  fi_softmax_kernel<<<(N_ + 255) / 256, 256, 0, stream>>>(wbuf, fibuf);
  node_kernel<<<N_, 256, 0, stream>>>(fibuf, emb, nodeb);

  // --- cosine similarity + top/bottom-k
  l2norm_kernel<<<N_, 256, 0, stream>>>(nodeb, xnb);
  gemm_bt_bf16<0><<<dim3(47, 47), 256, 0, stream>>>(xnb, xnb, nullptr, simb, N_, 256, N_);
  topk_kernel<<<N_, 256, 0, stream>>>(simb, topi, boti);

  // --- self branch
  gemm_bt_bf16<0><<<dim3(2, 47), 256, 0, stream>>>(nodeb, gatt, gat_bias, so, N_, 256, 256);

  // --- top GAT
  gemm_bt_bf16<0><<<dim3(2, 47), 256, 0, stream>>>(nodeb, gatt + 65536, nullptr, hbuf, N_, 256, 256);
  gat_esed_kernel<<<(N_ * H_ + 255) / 256, 256, 0, stream>>>(hbuf, gat_asrc + 256, gat_adst + 256, esb, edb);
  gat_init_kernel<<<N_, 256, 0, stream>>>(mu, sb, to);
  gat_edge_max_kernel<<<(E_ * H_ + 255) / 256, 256, 0, stream>>>(topi, esb, edb, mu);
  gat_edge_sum_kernel<<<(E_ * H_ + 255) / 256, 256, 0, stream>>>(topi, esb, edb, mu, sb, pb);
  gat_agg_kernel<<<E_, 256, 0, stream>>>(topi, pb, sb, hbuf, to);
  add_bias_kernel<<<(N_ * D_ + 255) / 256, 256, 0, stream>>>(to, gat_bias + 256);

  // --- bottom GAT
  gemm_bt_bf16<0><<<dim3(2, 47), 256, 0, stream>>>(nodeb, gatt + 131072, nullptr, hbuf, N_, 256, 256);
  gat_esed_kernel<<<(N_ * H_ + 255) / 256, 256, 0, stream>>>(hbuf, gat_asrc + 512, gat_adst + 512, esb, edb);
  gat_init_kernel<<<N_, 256, 0, stream>>>(mu, sb, bo);
  gat_edge_max_kernel<<<(E_ * H_ + 255) / 256, 256, 0, stream>>>(boti, esb, edb, mu);
  gat_edge_sum_kernel<<<(E_ * H_ + 255) / 256, 256, 0, stream>>>(boti, esb, edb, mu, sb, pb);
  gat_agg_kernel<<<E_, 256, 0, stream>>>(boti, pb, sb, hbuf, bo);
  add_bias_kernel<<<(N_ * D_ + 255) / 256, 256, 0, stream>>>(bo, gat_bias + 512);

  // --- gating fuse + double LN
  fuse_kernel<<<N_, 256, 0, stream>>>(so, to, bo, imp_W, imp_b, nodeb,
                                      ga_ln_g, ga_ln_b, fin_ln_g, fin_ln_b, outv);

  // --- predictor
  gemm_bt_bf16<1><<<dim3(4, 47), 256, 0, stream>>>(outv, pred1t, pred_b1, hid, N_, 256, 512);
  rowdot_kernel<<<N_, 256, 0, stream>>>(hid, pred_W2, pred_b2, (float*)d_out, 512);
}

// Round 4
// 3766.544 us; speedup vs baseline: 1.5296x; 1.0481x over previous
//
#include <hip/hip_runtime.h>
#include <hip/hip_bf16.h>
#include <math.h>

#define N_  6000
#define F_  16
#define S_  64
#define D_  256
#define H_  8
#define KK_ 32
#define L_  2
#define DH_ 32
#define E_  (N_*KK_ + N_)   // 198000 edges
#define NF_ (N_*F_)         // 96000 token rows
#define NC_ 750             // VA chunk: nodes per chunk
#define NCHUNK_ (N_/NC_)    // 8 chunks
#define CR_ (NC_*F_)        // 12000 rows per chunk

typedef float f32x4 __attribute__((ext_vector_type(4)));
typedef float f32v4 __attribute__((ext_vector_type(4)));
typedef __bf16 bf16_t;
typedef bf16_t bf16x8 __attribute__((ext_vector_type(8)));

// ---------------- device helpers ----------------

__device__ __forceinline__ float geluf(float x) {
  return 0.5f * x * (1.0f + erff(x * 0.7071067811865476f));
}
__device__ __forceinline__ float sigmf(float x) {
  return 1.0f / (1.0f + expf(-x));
}
__device__ __forceinline__ float block_sum_256(float v, float* red) {
  int tid = threadIdx.x;
  red[tid] = v; __syncthreads();
  #pragma unroll
  for (int s = 128; s > 0; s >>= 1) {
    if (tid < s) red[tid] += red[tid + s];
    __syncthreads();
  }
  float r = red[0];
  __syncthreads();
  return r;
}
// order-preserving float<->uint map (larger float => larger uint)
__device__ __forceinline__ unsigned fmap(float f) {
  unsigned u = __float_as_uint(f);
  return (u & 0x80000000u) ? ~u : (u | 0x80000000u);
}
__device__ __forceinline__ float funmap(unsigned u) {
  unsigned b = (u & 0x80000000u) ? (u ^ 0x80000000u) : ~u;
  return __uint_as_float(b);
}

// ---------------- weight prep ----------------
__global__ void transpose_kernel(const float* __restrict__ src, float* __restrict__ dst, int OUT) {
  int o = blockIdx.x, i = threadIdx.x;
  dst[(size_t)o * 256 + i] = src[(size_t)i * OUT + o];
}
__global__ void biascat_kernel(const float* __restrict__ bq, const float* __restrict__ bk,
                               const float* __restrict__ bv, float* __restrict__ dst) {
  int s = blockIdx.x, l = blockIdx.y, t = threadIdx.x;
  const float* p = (s == 0) ? bq : (s == 1) ? bk : bv;
  dst[l * 768 + s * 256 + t] = p[l * 256 + t];
}

// ---------------- GRU (fused einsum + gates, fp32) ----------------
__global__ __launch_bounds__(256)
void gru_kernel(const float* __restrict__ x, const float* __restrict__ Wih,
                const float* __restrict__ bih, const float* __restrict__ bhh,
                float* __restrict__ emb) {
  __shared__ float xs[64][33];
  __shared__ float ws[3][64][33];
  int nb = blockIdx.x * 64, kb = blockIdx.y * 64, f = blockIdx.z;
  int tid = threadIdx.x;
  int tx = tid & 15, ty = tid >> 4;
  float accR[4][4] = {}, accZ[4][4] = {}, accN[4][4] = {};
  for (int s0 = 0; s0 < S_; s0 += 32) {
    #pragma unroll
    for (int i = 0; i < 8; i++) {
      int idx = tid + i * 256;
      int n = idx >> 5, ss = idx & 31;
      int gn = nb + n;
      xs[n][ss] = (gn < N_) ? x[((size_t)gn * F_ + f) * S_ + s0 + ss] : 0.f;
    }
    #pragma unroll
    for (int g = 0; g < 3; g++)
      #pragma unroll
      for (int i = 0; i < 8; i++) {
        int idx = tid + i * 256;
        int k = idx >> 5, ss = idx & 31;
        ws[g][k][ss] = Wih[((size_t)f * 768 + g * 256 + kb + k) * S_ + s0 + ss];
      }
    __syncthreads();
    for (int ss = 0; ss < 32; ss++) {
      float a[4];
      #pragma unroll
      for (int i = 0; i < 4; i++) a[i] = xs[ty * 4 + i][ss];
      #pragma unroll
      for (int j = 0; j < 4; j++) {
        float wr = ws[0][tx * 4 + j][ss];
        float wz = ws[1][tx * 4 + j][ss];
        float wn = ws[2][tx * 4 + j][ss];
        #pragma unroll
        for (int i = 0; i < 4; i++) {
          accR[i][j] += a[i] * wr;
          accZ[i][j] += a[i] * wz;
          accN[i][j] += a[i] * wn;
        }
      }
    }
    __syncthreads();
  }
  #pragma unroll
  for (int i = 0; i < 4; i++) {
    int gn = nb + ty * 4 + i;
    if (gn >= N_) continue;
    #pragma unroll
    for (int j = 0; j < 4; j++) {
      int k = kb + tx * 4 + j;
      float r  = sigmf(accR[i][j] + bih[f * 768 + k]       + bhh[f * 768 + k]);
      float z  = sigmf(accZ[i][j] + bih[f * 768 + 256 + k] + bhh[f * 768 + 256 + k]);
      float ng = tanhf(accN[i][j] + bih[f * 768 + 512 + k] + r * bhh[f * 768 + 512 + k]);
      emb[((size_t)gn * F_ + f) * D_ + k] = (1.f - z) * ng;
    }
  }
}

// ---------------- bf16 MFMA GEMM (fp32 in/out) ----------------
template <int EPI>
__global__ __launch_bounds__(256)
void gemm_bt_bf16(const float* __restrict__ A, const float* __restrict__ Bt,
                  const float* __restrict__ bias, float* __restrict__ C,
                  int M, int K, int Nt) {
  __shared__ __align__(16) __hip_bfloat16 As[128 * 32];
  __shared__ __align__(16) __hip_bfloat16 Bs[128 * 32];
  int mb = blockIdx.y * 128, nb = blockIdx.x * 128;
  int tid = threadIdx.x;
  int lane = tid & 63, wid = tid >> 6;
  int wm = (wid >> 1) * 64, wn = (wid & 1) * 64;
  int q = lane >> 4, m16 = lane & 15;
  int arow = tid >> 1;
  int acol = (tid & 1) * 16;

  f32x4 acc[4][4];
  #pragma unroll
  for (int i = 0; i < 4; i++)
    #pragma unroll
    for (int j = 0; j < 4; j++) acc[i][j] = (f32x4){0.f, 0.f, 0.f, 0.f};

  for (int k0 = 0; k0 < K; k0 += 32) {
    {
      bool ok = (mb + arow) < M;
      const float* src = A + (size_t)(mb + arow) * K + k0 + acol;
      union { __hip_bfloat16 h[16]; uint4 u[2]; } tmp;
      #pragma unroll
      for (int v = 0; v < 4; v++) {
        f32v4 d = ok ? *reinterpret_cast<const f32v4*>(src + v * 4) : (f32v4){0.f,0.f,0.f,0.f};
        tmp.h[v * 4 + 0] = __float2bfloat16(d.x);
        tmp.h[v * 4 + 1] = __float2bfloat16(d.y);
        tmp.h[v * 4 + 2] = __float2bfloat16(d.z);
        tmp.h[v * 4 + 3] = __float2bfloat16(d.w);
      }
      uint4* dst = reinterpret_cast<uint4*>(&As[arow * 32 + acol]);
      dst[0] = tmp.u[0]; dst[1] = tmp.u[1];
    }
    {
      bool ok = (nb + arow) < Nt;
      const float* src = Bt + (size_t)(nb + arow) * K + k0 + acol;
      union { __hip_bfloat16 h[16]; uint4 u[2]; } tmp;
      #pragma unroll
      for (int v = 0; v < 4; v++) {
        f32v4 d = ok ? *reinterpret_cast<const f32v4*>(src + v * 4) : (f32v4){0.f,0.f,0.f,0.f};
        tmp.h[v * 4 + 0] = __float2bfloat16(d.x);
        tmp.h[v * 4 + 1] = __float2bfloat16(d.y);
        tmp.h[v * 4 + 2] = __float2bfloat16(d.z);
        tmp.h[v * 4 + 3] = __float2bfloat16(d.w);
      }
      uint4* dst = reinterpret_cast<uint4*>(&Bs[arow * 32 + acol]);
      dst[0] = tmp.u[0]; dst[1] = tmp.u[1];
    }
    __syncthreads();
    bf16x8 av[4], bv[4];
    #pragma unroll
    for (int mt = 0; mt < 4; mt++)
      av[mt] = *reinterpret_cast<const bf16x8*>(&As[(wm + mt * 16 + m16) * 32 + q * 8]);
    #pragma unroll
    for (int nt = 0; nt < 4; nt++)
      bv[nt] = *reinterpret_cast<const bf16x8*>(&Bs[(wn + nt * 16 + m16) * 32 + q * 8]);
    #pragma unroll
    for (int mt = 0; mt < 4; mt++)
      #pragma unroll
      for (int nt = 0; nt < 4; nt++)
        acc[mt][nt] = __builtin_amdgcn_mfma_f32_16x16x32_bf16(av[mt], bv[nt], acc[mt][nt], 0, 0, 0);
    __syncthreads();
  }
  #pragma unroll
  for (int mt = 0; mt < 4; mt++) {
    #pragma unroll
    for (int nt = 0; nt < 4; nt++) {
      #pragma unroll
      for (int r = 0; r < 4; r++) {
        int row = mb + wm + mt * 16 + q * 4 + r;
        int col = nb + wn + nt * 16 + m16;
        if (row < M && col < Nt) {
          float c = acc[mt][nt][r] + (bias ? bias[col] : 0.f);
          if (EPI == 1) c = geluf(c);
          C[(size_t)row * Nt + col] = c;
        }
      }
    }
  }
}

// ---------------- split-bf16 sim GEMM: C = xn @ xn^T at near-fp32 accuracy ----------------
__global__ __launch_bounds__(256)
void sim_split_kernel(const __hip_bfloat16* __restrict__ xh, const __hip_bfloat16* __restrict__ xl,
                      float* __restrict__ C) {
  __shared__ __align__(16) __hip_bfloat16 Ah[128 * 32];
  __shared__ __align__(16) __hip_bfloat16 Al[128 * 32];
  __shared__ __align__(16) __hip_bfloat16 Bh[128 * 32];
  __shared__ __align__(16) __hip_bfloat16 Bl[128 * 32];
  int mb = blockIdx.y * 128, nb = blockIdx.x * 128;
  int tid = threadIdx.x;
  int lane = tid & 63, wid = tid >> 6;
  int wm = (wid >> 1) * 64, wn = (wid & 1) * 64;
  int q = lane >> 4, m16 = lane & 15;
  int row = tid >> 1, halfk = (tid & 1) * 16;

  f32x4 acc[4][4];
  #pragma unroll
  for (int i = 0; i < 4; i++)
    #pragma unroll
    for (int j = 0; j < 4; j++) acc[i][j] = (f32x4){0.f, 0.f, 0.f, 0.f};

  uint4 z = {0u, 0u, 0u, 0u};
  for (int k0 = 0; k0 < 256; k0 += 32) {
    {
      int gr = mb + row; bool ok = gr < N_;
      const uint4* sh = reinterpret_cast<const uint4*>(xh + (size_t)gr * 256 + k0 + halfk);
      const uint4* sl = reinterpret_cast<const uint4*>(xl + (size_t)gr * 256 + k0 + halfk);
      uint4* dh = reinterpret_cast<uint4*>(&Ah[row * 32 + halfk]);
      uint4* dl = reinterpret_cast<uint4*>(&Al[row * 32 + halfk]);
      dh[0] = ok ? sh[0] : z; dh[1] = ok ? sh[1] : z;
      dl[0] = ok ? sl[0] : z; dl[1] = ok ? sl[1] : z;
    }
    {
      int gc = nb + row; bool ok = gc < N_;
      const uint4* sh = reinterpret_cast<const uint4*>(xh + (size_t)gc * 256 + k0 + halfk);
      const uint4* sl = reinterpret_cast<const uint4*>(xl + (size_t)gc * 256 + k0 + halfk);
      uint4* dh = reinterpret_cast<uint4*>(&Bh[row * 32 + halfk]);
      uint4* dl = reinterpret_cast<uint4*>(&Bl[row * 32 + halfk]);
      dh[0] = ok ? sh[0] : z; dh[1] = ok ? sh[1] : z;
      dl[0] = ok ? sl[0] : z; dl[1] = ok ? sl[1] : z;
    }
    __syncthreads();
    bf16x8 avh[4], avl[4], bvh[4], bvl[4];
    #pragma unroll
    for (int mt = 0; mt < 4; mt++) {
      avh[mt] = *reinterpret_cast<const bf16x8*>(&Ah[(wm + mt * 16 + m16) * 32 + q * 8]);
      avl[mt] = *reinterpret_cast<const bf16x8*>(&Al[(wm + mt * 16 + m16) * 32 + q * 8]);
    }
    #pragma unroll
    for (int nt = 0; nt < 4; nt++) {
      bvh[nt] = *reinterpret_cast<const bf16x8*>(&Bh[(wn + nt * 16 + m16) * 32 + q * 8]);
      bvl[nt] = *reinterpret_cast<const bf16x8*>(&Bl[(wn + nt * 16 + m16) * 32 + q * 8]);
    }
    #pragma unroll
    for (int mt = 0; mt < 4; mt++)
      #pragma unroll
      for (int nt = 0; nt < 4; nt++) {
        acc[mt][nt] = __builtin_amdgcn_mfma_f32_16x16x32_bf16(avh[mt], bvh[nt], acc[mt][nt], 0, 0, 0);
        acc[mt][nt] = __builtin_amdgcn_mfma_f32_16x16x32_bf16(avh[mt], bvl[nt], acc[mt][nt], 0, 0, 0);
        acc[mt][nt] = __builtin_amdgcn_mfma_f32_16x16x32_bf16(avl[mt], bvh[nt], acc[mt][nt], 0, 0, 0);
      }
    __syncthreads();
  }
  #pragma unroll
  for (int mt = 0; mt < 4; mt++)
    #pragma unroll
    for (int nt = 0; nt < 4; nt++)
      #pragma unroll
      for (int r = 0; r < 4; r++) {
        int rr = mb + wm + mt * 16 + q * 4 + r;
        int cc = nb + wn + nt * 16 + m16;
        if (rr < N_ && cc < N_) C[(size_t)rr * N_ + cc] = acc[mt][nt][r];
      }
}

// emb = LN(gelu(o) + emb)
__global__ __launch_bounds__(256)
void resid_gelu_ln_kernel(const float* __restrict__ o, float* __restrict__ emb,
                          const float* __restrict__ g, const float* __restrict__ b) {
  __shared__ float red[256];
  size_t row = blockIdx.x;
  int tid = threadIdx.x;
  float v = geluf(o[row * 256 + tid]) + emb[row * 256 + tid];
  float mean = block_sum_256(v, red) * (1.f / 256.f);
  float d = v - mean;
  float var = block_sum_256(d * d, red) * (1.f / 256.f);
  emb[row * 256 + tid] = d * rsqrtf(var + 1e-5f) * g[tid] + b[tid];
}

// ---------------- fused LN(q,k,v) + attention over F=16 tokens ----------------
// qkv: [NC,16,768] raw linear+bias; out: [NC,16,256] attention output
__global__ __launch_bounds__(256)
void attn_ln_kernel(const float* __restrict__ qkv, float* __restrict__ out,
                    const float* __restrict__ gq, const float* __restrict__ bq,
                    const float* __restrict__ gk, const float* __restrict__ bk,
                    const float* __restrict__ gv, const float* __restrict__ bv) {
  __shared__ float tile[16][772];
  int n = blockIdx.x, tid = threadIdx.x;
  size_t base = (size_t)n * 16 * 768;
  // load 16x768 (vector float4, coalesced)
  for (int i4 = tid; i4 < 16 * 768 / 4; i4 += 256) {
    int idx = i4 * 4;
    int f = idx / 768, cc = idx % 768;
    *reinterpret_cast<float4*>(&tile[f][cc]) =
        *reinterpret_cast<const float4*>(qkv + base + idx);
  }
  __syncthreads();
  // wave-level LN: 48 (row,slice) pairs, 12 per wave
  int lane = tid & 63, w = tid >> 6;
  for (int ii = 0; ii < 12; ii++) {
    int sl = w * 12 + ii;
    int s = sl >> 4, f = sl & 15;
    float* p = &tile[f][s * 256];
    float4 d = *reinterpret_cast<float4*>(p + lane * 4);
    float sum = d.x + d.y + d.z + d.w;
    #pragma unroll
    for (int m = 1; m < 64; m <<= 1) sum += __shfl_xor(sum, m, 64);
    float mean = sum * (1.f / 256.f);
    float e0 = d.x - mean, e1 = d.y - mean, e2 = d.z - mean, e3 = d.w - mean;
    float sq = e0 * e0 + e1 * e1 + e2 * e2 + e3 * e3;
    #pragma unroll
    for (int m = 1; m < 64; m <<= 1) sq += __shfl_xor(sq, m, 64);
    float inv = rsqrtf(sq * (1.f / 256.f) + 1e-5f);
    const float* g  = (s == 0) ? gq : (s == 1) ? gk : gv;
    const float* bb = (s == 0) ? bq : (s == 1) ? bk : bv;
    float4 gg = *reinterpret_cast<const float4*>(g + lane * 4);
    float4 bo = *reinterpret_cast<const float4*>(bb + lane * 4);
    d.x = e0 * inv * gg.x + bo.x;
    d.y = e1 * inv * gg.y + bo.y;
    d.z = e2 * inv * gg.z + bo.z;
    d.w = e3 * inv * gg.w + bo.w;
    *reinterpret_cast<float4*>(p + lane * 4) = d;
  }
  __syncthreads();
  // attention: c = query token, h = head, half = output d-range
  int c = tid & 15, h = (tid >> 4) & 7, half = tid >> 7;
  const float scale = 0.17677669529663687f;  // 1/sqrt(32)
  float sc[16];
  float mx = -3e38f;
  #pragma unroll
  for (int s = 0; s < 16; s++) {
    float acc = 0.f;
    #pragma unroll
    for (int e = 0; e < 32; e++)
      acc += tile[c][h * 32 + e] * tile[s][256 + h * 32 + e];
    sc[s] = acc * scale;
    mx = fmaxf(mx, sc[s]);
  }
  float sum = 0.f;
  #pragma unroll
  for (int s = 0; s < 16; s++) { sc[s] = expf(sc[s] - mx); sum += sc[s]; }
  float inv = 1.f / sum;
  #pragma unroll
  for (int dd = 0; dd < 16; dd++) {
    int d = half * 16 + dd;
    float acc = 0.f;
    #pragma unroll
    for (int s = 0; s < 16; s++) acc += sc[s] * tile[s][512 + h * 32 + d];
    out[((size_t)n * 16 + c) * 256 + h * 32 + d] = acc * inv;
  }
}

// ---------------- feature importance ----------------
__global__ __launch_bounds__(256)
void rowdot_kernel(const float* __restrict__ A, const float* __restrict__ w,
                   const float* __restrict__ bscalar, float* __restrict__ out, int K) {
  __shared__ float red[256];
  int row = blockIdx.x, tid = threadIdx.x;
  float acc = 0.f;
  for (int d = tid; d < K; d += 256) acc += A[(size_t)row * K + d] * w[d];
  float s = block_sum_256(acc, red);
  if (tid == 0) out[row] = s + bscalar[0];
}

__global__ void fi_softmax_kernel(const float* __restrict__ w, float* __restrict__ fi) {
  int n = blockIdx.x * 256 + threadIdx.x;
  if (n >= N_) return;
  float mx = -3e38f;
  for (int f = 0; f < 16; f++) mx = fmaxf(mx, w[n * 16 + f]);
  float e[16], s = 0.f;
  for (int f = 0; f < 16; f++) { e[f] = expf(w[n * 16 + f] - mx); s += e[f]; }
  float inv = 1.f / s;
  for (int f = 0; f < 16; f++) fi[n * 16 + f] = e[f] * inv;
}

__global__ __launch_bounds__(256)
void node_kernel(const float* __restrict__ fi, const float* __restrict__ emb,
                 float* __restrict__ node) {
  int n = blockIdx.x, d = threadIdx.x;
  float acc = 0.f;
  for (int f = 0; f < 16; f++)
    acc += fi[n * 16 + f] * emb[((size_t)n * 16 + f) * 256 + d];
  node[(size_t)n * 256 + d] = acc;
}

// l2-normalize + split into bf16 hi/lo
__global__ __launch_bounds__(256)
void l2norm_split_kernel(const float* __restrict__ in, __hip_bfloat16* __restrict__ xh,
                         __hip_bfloat16* __restrict__ xl) {
  __shared__ float red[256];
  size_t row = blockIdx.x;
  int tid = threadIdx.x;
  float v = in[row * 256 + tid];
  float ss = block_sum_256(v * v, red);
  float y = v * rsqrtf(ss + 1e-12f);
  __hip_bfloat16 h = __float2bfloat16(y);
  xh[row * 256 + tid] = h;
  xl[row * 256 + tid] = __float2bfloat16(y - __bfloat162float(h));
}

// ---------------- top-k / bottom-k: register-cached radix select ----------------
__global__ __launch_bounds__(256)
void topk_kernel(const float* __restrict__ sim, int* __restrict__ top,
                 int* __restrict__ bot) {
  __shared__ unsigned cval[N_];
  __shared__ unsigned short cidx[N_];
  __shared__ unsigned hist[4][257];
  __shared__ unsigned suf[257];
  __shared__ unsigned s_b, s_r, s_cnt, s_out;
  int i = blockIdx.x, tid = threadIdx.x;
  int wid = tid >> 6;
  unsigned raw[24];
  #pragma unroll
  for (int k = 0; k < 24; k++) {
    int j = tid + k * 256;
    unsigned w = 0;
    if (j < N_ && j != i) w = fmap(sim[(size_t)i * N_ + j]);
    raw[k] = w;
  }
  for (int pass = 0; pass < 2; pass++) {
    int* dst = pass ? bot : top;
    // round 1: byte-0 histogram (per-wave copies)
    #pragma unroll
    for (int w4 = 0; w4 < 4; w4++) hist[w4][tid] = 0;
    if (tid == 0) { s_r = KK_; s_cnt = 0; s_out = 0; }
    __syncthreads();
    #pragma unroll
    for (int k = 0; k < 24; k++) {
      unsigned w = raw[k]; if (pass && w) w = ~w;
      if (w) atomicAdd(&hist[wid][w >> 24], 1u);
    }
    __syncthreads();
    suf[tid] = hist[0][tid] + hist[1][tid] + hist[2][tid] + hist[3][tid];
    __syncthreads();
    for (int s = 1; s < 256; s <<= 1) {
      unsigned add = (tid + s < 256) ? suf[tid + s] : 0u;
      __syncthreads();
      suf[tid] += add;
      __syncthreads();
    }
    {
      unsigned rK = s_r;
      __syncthreads();
      unsigned above = (tid < 255) ? suf[tid + 1] : 0u;
      if (suf[tid] >= rK && above < rK) { s_b = (unsigned)tid; s_r = rK - above; }
    }
    __syncthreads();
    unsigned prefix = s_b;
    // round 2: compact byte0 == prefix
    #pragma unroll
    for (int k = 0; k < 24; k++) {
      unsigned w = raw[k]; if (pass && w) w = ~w;
      if (w && (w >> 24) == prefix) {
        unsigned p = atomicAdd(&s_cnt, 1u);
        cval[p] = w; cidx[p] = (unsigned short)(tid + k * 256);
      }
    }
    __syncthreads();
    int c = (int)s_cnt;
    // rounds: bytes 1..3 on compacted list
    for (int lvl = 1; lvl < 4; lvl++) {
      int sh = 24 - 8 * lvl;
      #pragma unroll
      for (int w4 = 0; w4 < 4; w4++) hist[w4][tid] = 0;
      __syncthreads();
      for (int idx = tid; idx < c; idx += 256) {
        unsigned w = cval[idx];
        if ((w >> (sh + 8)) == prefix) atomicAdd(&hist[wid][(w >> sh) & 255u], 1u);
      }
      __syncthreads();
      suf[tid] = hist[0][tid] + hist[1][tid] + hist[2][tid] + hist[3][tid];
      __syncthreads();
      for (int s = 1; s < 256; s <<= 1) {
        unsigned add = (tid + s < 256) ? suf[tid + s] : 0u;
        __syncthreads();
        suf[tid] += add;
        __syncthreads();
      }
      {
        unsigned rK = s_r;
        __syncthreads();
        unsigned above = (tid < 255) ? suf[tid + 1] : 0u;
        if (suf[tid] >= rK && above < rK) { s_b = (unsigned)tid; s_r = rK - above; }
      }
      __syncthreads();
      prefix = (prefix << 8) | s_b;
    }
    unsigned T = prefix;
    // collect strictly greater than T
    #pragma unroll
    for (int k = 0; k < 24; k++) {
      unsigned w = raw[k]; if (pass && w) w = ~w;
      if (w > T) {
        unsigned p = atomicAdd(&s_out, 1u);
        dst[i * KK_ + p] = tid + k * 256;
      }
    }
    __syncthreads();
    // ties: take lowest indices
    int rr = (int)s_r;
    int basep = KK_ - rr;
    int last = -1;
    for (int t = 0; t < rr; t++) {
      unsigned best = 0xffffffffu;
      for (int idx = tid; idx < c; idx += 256) {
        if (cval[idx] == T) {
          int j = (int)cidx[idx];
          if (j > last && (unsigned)j < best) best = (unsigned)j;
        }
      }
      suf[tid] = best;
      __syncthreads();
      #pragma unroll
      for (int s = 128; s > 0; s >>= 1) {
        if (tid < s) suf[tid] = min(suf[tid], suf[tid + s]);
        __syncthreads();
      }
      last = (int)suf[0];
      if (tid == 0) dst[i * KK_ + basep + t] = last;
      __syncthreads();
    }
    __syncthreads();
  }
}

// ---------------- GAT ----------------
__global__ void gat_esed_kernel(const float* __restrict__ h, const float* __restrict__ asrc,
                                const float* __restrict__ adst,
                                float* __restrict__ es, float* __restrict__ ed) {
  int idx = blockIdx.x * 256 + threadIdx.x;
  if (idx >= N_ * H_) return;
  int hh = idx & 7;
  const float* hp = h + (size_t)(idx >> 3) * 256 + hh * 32;
  float a = 0.f, b = 0.f;
  for (int d = 0; d < 32; d++) {
    float hv = hp[d];
    a += hv * asrc[hh * 32 + d];
    b += hv * adst[hh * 32 + d];
  }
  es[idx] = a; ed[idx] = b;
}

__global__ void gat_init_kernel(unsigned* __restrict__ m_u, float* __restrict__ sbuf,
                                float* __restrict__ out) {
  int idx = blockIdx.x * 256 + threadIdx.x;
  if (idx < N_ * H_) { m_u[idx] = fmap(-1e9f); sbuf[idx] = 0.f; }
  if (idx < N_ * D_) out[idx] = 0.f;
}

__device__ __forceinline__ void edge_decode(int e, const int* nbr, int& src, int& tgt, bool& valid) {
  if (e < N_ * KK_) { src = e / KK_; tgt = nbr[e]; valid = (src != tgt); }
  else { src = tgt = e - N_ * KK_; valid = true; }
}

__global__ void gat_edge_max_kernel(const int* __restrict__ nbr, const float* __restrict__ es,
                                    const float* __restrict__ ed, unsigned* __restrict__ m_u) {
  int t = blockIdx.x * 256 + threadIdx.x;
  if (t >= E_ * H_) return;
  int e = t >> 3, hh = t & 7;
  int src, tgt; bool valid;
  edge_decode(e, nbr, src, tgt, valid);
  float ev = -1e9f;
  if (valid) {
    float xv = es[src * H_ + hh] + ed[tgt * H_ + hh];
    ev = xv > 0.f ? xv : 0.2f * xv;
  }
  atomicMax(&m_u[tgt * H_ + hh], fmap(ev));
}

__global__ void gat_edge_sum_kernel(const int* __restrict__ nbr, const float* __restrict__ es,
                                    const float* __restrict__ ed, const unsigned* __restrict__ m_u,
                                    float* __restrict__ sbuf, float* __restrict__ p) {
  int t = blockIdx.x * 256 + threadIdx.x;
  if (t >= E_ * H_) return;
  int e = t >> 3, hh = t & 7;
  int src, tgt; bool valid;
  edge_decode(e, nbr, src, tgt, valid);
  float pv = 0.f;
  if (valid) {
    float xv = es[src * H_ + hh] + ed[tgt * H_ + hh];
    float ev = xv > 0.f ? xv : 0.2f * xv;
    pv = expf(ev - funmap(m_u[tgt * H_ + hh]));
  }
  p[t] = pv;
  if (pv != 0.f) atomicAdd(&sbuf[tgt * H_ + hh], pv);
}

__global__ __launch_bounds__(256)
void gat_agg_kernel(const int* __restrict__ nbr, const float* __restrict__ p,
                    const float* __restrict__ sbuf, const float* __restrict__ h,
                    float* __restrict__ out) {
  long long t = (long long)blockIdx.x * 256 + threadIdx.x;
  if (t >= (long long)E_ * 256) return;
  int e = (int)(t >> 8), d = (int)(t & 255), hh = d >> 5;
  int src, tgt; bool valid;
  edge_decode(e, nbr, src, tgt, valid);
  float pv = p[e * H_ + hh];
  if (pv == 0.f) return;
  float alpha = pv / (sbuf[tgt * H_ + hh] + 1e-16f);
  atomicAdd(&out[(size_t)tgt * 256 + d], alpha * h[(size_t)src * 256 + d]);
}

__global__ void add_bias_kernel(float* __restrict__ out, const float* __restrict__ bias) {
  int idx = blockIdx.x * 256 + threadIdx.x;
  if (idx < N_ * D_) out[idx] += bias[idx & 255];
}

// ---------------- gating fuse + double LN ----------------
__global__ __launch_bounds__(256)
void fuse_kernel(const float* __restrict__ so, const float* __restrict__ to,
                 const float* __restrict__ bo, const float* __restrict__ impW,
                 const float* __restrict__ impb, const float* __restrict__ node,
                 const float* __restrict__ gag, const float* __restrict__ gab,
                 const float* __restrict__ fing, const float* __restrict__ finb,
                 float* __restrict__ outv) {
  __shared__ float red[256];
  size_t row = blockIdx.x;
  int tid = threadIdx.x;
  float s0 = so[row * 256 + tid];
  float t0 = to[row * 256 + tid];
  float b0 = bo[row * 256 + tid];
  float l0 = block_sum_256(s0 * impW[tid], red) + impb[0];
  float l1 = block_sum_256(t0 * impW[256 + tid], red) + impb[1];
  float l2 = block_sum_256(b0 * impW[512 + tid], red) + impb[2];
  float mx = fmaxf(l0, fmaxf(l1, l2));
  float e0 = expf(l0 - mx), e1 = expf(l1 - mx), e2 = expf(l2 - mx);
  float inv = 1.f / (e0 + e1 + e2);
  float fused = (e0 * s0 + e1 * t0 + e2 * b0) * inv;
  float v = geluf(fused) + node[row * 256 + tid];
  float mean = block_sum_256(v, red) * (1.f / 256.f);
  float d = v - mean;
  float var = block_sum_256(d * d, red) * (1.f / 256.f);
  float y = d * rsqrtf(var + 1e-5f) * gag[tid] + gab[tid];
  mean = block_sum_256(y, red) * (1.f / 256.f);
  d = y - mean;
  var = block_sum_256(d * d, red) * (1.f / 256.f);
  outv[row * 256 + tid] = d * rsqrtf(var + 1e-5f) * fing[tid] + finb[tid];
}

// ---------------- host launch ----------------
// Workspace (floats), peak 41,431,040 fl = 165.8 MB (< proven-safe 172 MB):
//   emb 0..24,576,000 | qkvbuf 24,576,000..33,792,000 | obuf 33,792,000..36,864,000
//   wbuf 36,864,000 | fibuf 36,960,000 | nodeb 37,056,000..38,592,000
//   xh (bf16) 38,592,000..39,360,000 | xl (bf16) 39,360,000..40,128,000
//   topi 40,128,000 | boti 40,320,000 | wtb 40,512,000..41,431,040
//   sim overlays 0..36,000,000; post-topk smalls overlay dead sim [0..12,528,000)
extern "C" void kernel_launch(void* const* d_in, const int* in_sizes, int n_in,
                              void* d_out, int out_size, void* d_ws, size_t ws_size,
                              hipStream_t stream) {
  const float* x        = (const float*)d_in[0];
  const float* gru_Wih  = (const float*)d_in[1];
  const float* gru_bih  = (const float*)d_in[2];
  const float* gru_bhh  = (const float*)d_in[3];
  const float* va_Wq    = (const float*)d_in[4];
  const float* va_bq    = (const float*)d_in[5];
  const float* va_Wk    = (const float*)d_in[6];
  const float* va_bk    = (const float*)d_in[7];
  const float* va_Wv    = (const float*)d_in[8];
  const float* va_bv    = (const float*)d_in[9];
  const float* va_lnq_g = (const float*)d_in[10];
  const float* va_lnq_b = (const float*)d_in[11];
  const float* va_lnk_g = (const float*)d_in[12];
  const float* va_lnk_b = (const float*)d_in[13];
  const float* va_lnv_g = (const float*)d_in[14];
  const float* va_lnv_b = (const float*)d_in[15];
  const float* va_Wo    = (const float*)d_in[16];
  const float* va_bo    = (const float*)d_in[17];
  const float* va_ln_g  = (const float*)d_in[18];
  const float* va_ln_b  = (const float*)d_in[19];
  const float* va_fi_W1 = (const float*)d_in[20];
  const float* va_fi_b1 = (const float*)d_in[21];
  const float* va_fi_W2 = (const float*)d_in[22];
  const float* va_fi_b2 = (const float*)d_in[23];
  const float* gat_W    = (const float*)d_in[24];
  const float* gat_asrc = (const float*)d_in[25];
  const float* gat_adst = (const float*)d_in[26];
  const float* gat_bias = (const float*)d_in[27];
  const float* imp_W    = (const float*)d_in[28];
  const float* imp_b    = (const float*)d_in[29];
  const float* ga_ln_g  = (const float*)d_in[30];
  const float* ga_ln_b  = (const float*)d_in[31];
  const float* fin_ln_g = (const float*)d_in[32];
  const float* fin_ln_b = (const float*)d_in[33];
  const float* pred_W1  = (const float*)d_in[34];
  const float* pred_b1  = (const float*)d_in[35];
  const float* pred_W2  = (const float*)d_in[36];
  const float* pred_b2  = (const float*)d_in[37];

  float* base   = (float*)d_ws;
  float* emb    = base;
  float* qkvbuf = base + 24576000;
  float* obuf   = base + 33792000;
  float* wbuf   = base + 36864000;
  float* fibuf  = base + 36960000;
  float* nodeb  = base + 37056000;
  __hip_bfloat16* xh = (__hip_bfloat16*)(base + 38592000);
  __hip_bfloat16* xl = (__hip_bfloat16*)(base + 39360000);
  int*   topi   = (int*)(base + 40128000);
  int*   boti   = (int*)(base + 40320000);
  float* wtb    = base + 40512000;
  float* simb   = base;
  // post-topk overlays:
  float* so     = base + 0;
  float* to     = base + 1536000;
  float* bo     = base + 3072000;
  float* hbuf   = base + 4608000;
  float* esb    = base + 6144000;
  float* edb    = base + 6192000;
  unsigned* mu  = (unsigned*)(base + 6240000);
  float* sb     = base + 6288000;
  float* pb     = base + 6336000;
  float* outv   = base + 7920000;
  float* hid    = base + 9456000;

  // wtb sub-offsets
  float* qkvt0  = wtb + 0;
  float* qkvt1  = wtb + 196608;
  float* wot0   = wtb + 393216;
  float* wot1   = wtb + 458752;
  float* fi1t   = wtb + 524288;
  float* gatt   = wtb + 589824;
  float* pred1t = wtb + 786432;
  float* qkvb   = wtb + 917504;

  // --- weight prep
  transpose_kernel<<<256, 256, 0, stream>>>(va_Wq,           qkvt0,          256);
  transpose_kernel<<<256, 256, 0, stream>>>(va_Wk,           qkvt0 + 65536,  256);
  transpose_kernel<<<256, 256, 0, stream>>>(va_Wv,           qkvt0 + 131072, 256);
  transpose_kernel<<<256, 256, 0, stream>>>(va_Wq + 65536,   qkvt1,          256);
  transpose_kernel<<<256, 256, 0, stream>>>(va_Wk + 65536,   qkvt1 + 65536,  256);
  transpose_kernel<<<256, 256, 0, stream>>>(va_Wv + 65536,   qkvt1 + 131072, 256);
  transpose_kernel<<<256, 256, 0, stream>>>(va_Wo,           wot0,           256);
  transpose_kernel<<<256, 256, 0, stream>>>(va_Wo + 65536,   wot1,           256);
  transpose_kernel<<<256, 256, 0, stream>>>(va_fi_W1 + (L_-1)*65536, fi1t,   256);
  transpose_kernel<<<256, 256, 0, stream>>>(gat_W,           gatt,           256);
  transpose_kernel<<<256, 256, 0, stream>>>(gat_W + 65536,   gatt + 65536,   256);
  transpose_kernel<<<256, 256, 0, stream>>>(gat_W + 131072,  gatt + 131072,  256);
  transpose_kernel<<<512, 256, 0, stream>>>(pred_W1,         pred1t,         512);
  biascat_kernel<<<dim3(3, 2), 256, 0, stream>>>(va_bq, va_bk, va_bv, qkvb);

  // --- TimeMixing GRU
  gru_kernel<<<dim3(94, 4, 16), 256, 0, stream>>>(x, gru_Wih, gru_bih, gru_bhh, emb);

  // --- Variable attention layers (fused qkv GEMM + fused LN+attn)
  for (int l = 0; l < L_; l++) {
    const float* qkvt = l ? qkvt1 : qkvt0;
    const float* wot  = l ? wot1  : wot0;
    for (int c = 0; c < NCHUNK_; c++) {
      float* embc = emb + (size_t)c * NC_ * F_ * D_;
      gemm_bt_bf16<0><<<dim3(6, 94), 256, 0, stream>>>(embc, qkvt, qkvb + l * 768,
                                                       qkvbuf, CR_, 256, 768);
      attn_ln_kernel<<<NC_, 256, 0, stream>>>(qkvbuf, obuf,
                                              va_lnq_g + l * 256, va_lnq_b + l * 256,
                                              va_lnk_g + l * 256, va_lnk_b + l * 256,
                                              va_lnv_g + l * 256, va_lnv_b + l * 256);
      gemm_bt_bf16<0><<<dim3(2, 94), 256, 0, stream>>>(obuf, wot, va_bo + l * 256,
                                                       qkvbuf, CR_, 256, 256);
      resid_gelu_ln_kernel<<<CR_, 256, 0, stream>>>(qkvbuf, embc, va_ln_g + l * 256, va_ln_b + l * 256);
    }
  }

  // --- feature importance
  for (int c = 0; c < NCHUNK_; c++) {
    float* embc = emb + (size_t)c * NC_ * F_ * D_;
    gemm_bt_bf16<1><<<dim3(2, 94), 256, 0, stream>>>(embc, fi1t, va_fi_b1 + (L_-1) * 256,
                                                     obuf, CR_, 256, 256);
    rowdot_kernel<<<CR_, 256, 0, stream>>>(obuf, va_fi_W2 + (L_-1) * 256, va_fi_b2 + (L_-1),
                                           wbuf + (size_t)c * CR_, 256);
  }
  fi_softmax_kernel<<<(N_ + 255) / 256, 256, 0, stream>>>(wbuf, fibuf);
  node_kernel<<<N_, 256, 0, stream>>>(fibuf, emb, nodeb);

  // --- cosine similarity (split-bf16, fp32-grade) + top/bottom-k
  l2norm_split_kernel<<<N_, 256, 0, stream>>>(nodeb, xh, xl);
  sim_split_kernel<<<dim3(47, 47), 256, 0, stream>>>(xh, xl, simb);
  topk_kernel<<<N_, 256, 0, stream>>>(simb, topi, boti);

  // --- self branch
  gemm_bt_bf16<0><<<dim3(2, 47), 256, 0, stream>>>(nodeb, gatt, gat_bias, so, N_, 256, 256);

  // --- top GAT
  gemm_bt_bf16<0><<<dim3(2, 47), 256, 0, stream>>>(nodeb, gatt + 65536, nullptr, hbuf, N_, 256, 256);
  gat_esed_kernel<<<(N_ * H_ + 255) / 256, 256, 0, stream>>>(hbuf, gat_asrc + 256, gat_adst + 256, esb, edb);
  gat_init_kernel<<<N_, 256, 0, stream>>>(mu, sb, to);
  gat_edge_max_kernel<<<(E_ * H_ + 255) / 256, 256, 0, stream>>>(topi, esb, edb, mu);
  gat_edge_sum_kernel<<<(E_ * H_ + 255) / 256, 256, 0, stream>>>(topi, esb, edb, mu, sb, pb);
  gat_agg_kernel<<<E_, 256, 0, stream>>>(topi, pb, sb, hbuf, to);
  add_bias_kernel<<<(N_ * D_ + 255) / 256, 256, 0, stream>>>(to, gat_bias + 256);

  // --- bottom GAT
  gemm_bt_bf16<0><<<dim3(2, 47), 256, 0, stream>>>(nodeb, gatt + 131072, nullptr, hbuf, N_, 256, 256);
  gat_esed_kernel<<<(N_ * H_ + 255) / 256, 256, 0, stream>>>(hbuf, gat_asrc + 512, gat_adst + 512, esb, edb);
  gat_init_kernel<<<N_, 256, 0, stream>>>(mu, sb, bo);
  gat_edge_max_kernel<<<(E_ * H_ + 255) / 256, 256, 0, stream>>>(boti, esb, edb, mu);
  gat_edge_sum_kernel<<<(E_ * H_ + 255) / 256, 256, 0, stream>>>(boti, esb, edb, mu, sb, pb);
  gat_agg_kernel<<<E_, 256, 0, stream>>>(boti, pb, sb, hbuf, bo);
  add_bias_kernel<<<(N_ * D_ + 255) / 256, 256, 0, stream>>>(bo, gat_bias + 512);

  // --- gating fuse + double LN
  fuse_kernel<<<N_, 256, 0, stream>>>(so, to, bo, imp_W, imp_b, nodeb,
                                      ga_ln_g, ga_ln_b, fin_ln_g, fin_ln_b, outv);

  // --- predictor
  gemm_bt_bf16<1><<<dim3(4, 47), 256, 0, stream>>>(outv, pred1t, pred_b1, hid, N_, 256, 512);
  rowdot_kernel<<<N_, 256, 0, stream>>>(hid, pred_W2, pred_b2, (float*)d_out, 512);
}

// Round 5
// 3484.755 us; speedup vs baseline: 1.6533x; 1.0809x over previous
//
#include <hip/hip_runtime.h>
#include <hip/hip_bf16.h>
#include <math.h>

#define N_  6000
#define F_  16
#define S_  64
#define D_  256
#define H_  8
#define KK_ 32
#define L_  2
#define DH_ 32
#define E_  (N_*KK_ + N_)   // 198000 edges
#define NF_ (N_*F_)         // 96000 token rows
#define NC_ 750             // VA chunk: nodes per chunk
#define NCHUNK_ (N_/NC_)    // 8 chunks
#define CR_ (NC_*F_)        // 12000 rows per chunk

typedef float f32x4 __attribute__((ext_vector_type(4)));
typedef float f32v4 __attribute__((ext_vector_type(4)));
typedef __bf16 bf16_t;
typedef bf16_t bf16x8 __attribute__((ext_vector_type(8)));

// ---------------- device helpers ----------------

__device__ __forceinline__ float geluf(float x) {
  return 0.5f * x * (1.0f + erff(x * 0.7071067811865476f));
}
__device__ __forceinline__ float sigmf(float x) {
  return 1.0f / (1.0f + expf(-x));
}
__device__ __forceinline__ float block_sum_256(float v, float* red) {
  int tid = threadIdx.x;
  red[tid] = v; __syncthreads();
  #pragma unroll
  for (int s = 128; s > 0; s >>= 1) {
    if (tid < s) red[tid] += red[tid + s];
    __syncthreads();
  }
  float r = red[0];
  __syncthreads();
  return r;
}
// order-preserving float<->uint map (larger float => larger uint)
__device__ __forceinline__ unsigned fmap(float f) {
  unsigned u = __float_as_uint(f);
  return (u & 0x80000000u) ? ~u : (u | 0x80000000u);
}
__device__ __forceinline__ float funmap(unsigned u) {
  unsigned b = (u & 0x80000000u) ? (u ^ 0x80000000u) : ~u;
  return __uint_as_float(b);
}

// ---------------- weight prep ----------------
__global__ void transpose_kernel(const float* __restrict__ src, float* __restrict__ dst, int OUT) {
  int o = blockIdx.x, i = threadIdx.x;
  dst[(size_t)o * 256 + i] = src[(size_t)i * OUT + o];
}
__global__ void biascat_kernel(const float* __restrict__ bq, const float* __restrict__ bk,
                               const float* __restrict__ bv, float* __restrict__ dst) {
  int s = blockIdx.x, l = blockIdx.y, t = threadIdx.x;
  const float* p = (s == 0) ? bq : (s == 1) ? bk : bv;
  dst[l * 768 + s * 256 + t] = p[l * 256 + t];
}

// ---------------- GRU (fused einsum + gates, fp32) ----------------
__global__ __launch_bounds__(256)
void gru_kernel(const float* __restrict__ x, const float* __restrict__ Wih,
                const float* __restrict__ bih, const float* __restrict__ bhh,
                float* __restrict__ emb) {
  __shared__ float xs[64][33];
  __shared__ float ws[3][64][33];
  int nb = blockIdx.x * 64, kb = blockIdx.y * 64, f = blockIdx.z;
  int tid = threadIdx.x;
  int tx = tid & 15, ty = tid >> 4;
  float accR[4][4] = {}, accZ[4][4] = {}, accN[4][4] = {};
  for (int s0 = 0; s0 < S_; s0 += 32) {
    #pragma unroll
    for (int i = 0; i < 8; i++) {
      int idx = tid + i * 256;
      int n = idx >> 5, ss = idx & 31;
      int gn = nb + n;
      xs[n][ss] = (gn < N_) ? x[((size_t)gn * F_ + f) * S_ + s0 + ss] : 0.f;
    }
    #pragma unroll
    for (int g = 0; g < 3; g++)
      #pragma unroll
      for (int i = 0; i < 8; i++) {
        int idx = tid + i * 256;
        int k = idx >> 5, ss = idx & 31;
        ws[g][k][ss] = Wih[((size_t)f * 768 + g * 256 + kb + k) * S_ + s0 + ss];
      }
    __syncthreads();
    for (int ss = 0; ss < 32; ss++) {
      float a[4];
      #pragma unroll
      for (int i = 0; i < 4; i++) a[i] = xs[ty * 4 + i][ss];
      #pragma unroll
      for (int j = 0; j < 4; j++) {
        float wr = ws[0][tx * 4 + j][ss];
        float wz = ws[1][tx * 4 + j][ss];
        float wn = ws[2][tx * 4 + j][ss];
        #pragma unroll
        for (int i = 0; i < 4; i++) {
          accR[i][j] += a[i] * wr;
          accZ[i][j] += a[i] * wz;
          accN[i][j] += a[i] * wn;
        }
      }
    }
    __syncthreads();
  }
  #pragma unroll
  for (int i = 0; i < 4; i++) {
    int gn = nb + ty * 4 + i;
    if (gn >= N_) continue;
    #pragma unroll
    for (int j = 0; j < 4; j++) {
      int k = kb + tx * 4 + j;
      float r  = sigmf(accR[i][j] + bih[f * 768 + k]       + bhh[f * 768 + k]);
      float z  = sigmf(accZ[i][j] + bih[f * 768 + 256 + k] + bhh[f * 768 + 256 + k]);
      float ng = tanhf(accN[i][j] + bih[f * 768 + 512 + k] + r * bhh[f * 768 + 512 + k]);
      emb[((size_t)gn * F_ + f) * D_ + k] = (1.f - z) * ng;
    }
  }
}

// ---------------- bf16 MFMA GEMM (fp32 in/out) ----------------
template <int EPI>
__global__ __launch_bounds__(256)
void gemm_bt_bf16(const float* __restrict__ A, const float* __restrict__ Bt,
                  const float* __restrict__ bias, float* __restrict__ C,
                  int M, int K, int Nt) {
  __shared__ __align__(16) __hip_bfloat16 As[128 * 32];
  __shared__ __align__(16) __hip_bfloat16 Bs[128 * 32];
  int mb = blockIdx.y * 128, nb = blockIdx.x * 128;
  int tid = threadIdx.x;
  int lane = tid & 63, wid = tid >> 6;
  int wm = (wid >> 1) * 64, wn = (wid & 1) * 64;
  int q = lane >> 4, m16 = lane & 15;
  int arow = tid >> 1;
  int acol = (tid & 1) * 16;

  f32x4 acc[4][4];
  #pragma unroll
  for (int i = 0; i < 4; i++)
    #pragma unroll
    for (int j = 0; j < 4; j++) acc[i][j] = (f32x4){0.f, 0.f, 0.f, 0.f};

  for (int k0 = 0; k0 < K; k0 += 32) {
    {
      bool ok = (mb + arow) < M;
      const float* src = A + (size_t)(mb + arow) * K + k0 + acol;
      union { __hip_bfloat16 h[16]; uint4 u[2]; } tmp;
      #pragma unroll
      for (int v = 0; v < 4; v++) {
        f32v4 d = ok ? *reinterpret_cast<const f32v4*>(src + v * 4) : (f32v4){0.f,0.f,0.f,0.f};
        tmp.h[v * 4 + 0] = __float2bfloat16(d.x);
        tmp.h[v * 4 + 1] = __float2bfloat16(d.y);
        tmp.h[v * 4 + 2] = __float2bfloat16(d.z);
        tmp.h[v * 4 + 3] = __float2bfloat16(d.w);
      }
      uint4* dst = reinterpret_cast<uint4*>(&As[arow * 32 + acol]);
      dst[0] = tmp.u[0]; dst[1] = tmp.u[1];
    }
    {
      bool ok = (nb + arow) < Nt;
      const float* src = Bt + (size_t)(nb + arow) * K + k0 + acol;
      union { __hip_bfloat16 h[16]; uint4 u[2]; } tmp;
      #pragma unroll
      for (int v = 0; v < 4; v++) {
        f32v4 d = ok ? *reinterpret_cast<const f32v4*>(src + v * 4) : (f32v4){0.f,0.f,0.f,0.f};
        tmp.h[v * 4 + 0] = __float2bfloat16(d.x);
        tmp.h[v * 4 + 1] = __float2bfloat16(d.y);
        tmp.h[v * 4 + 2] = __float2bfloat16(d.z);
        tmp.h[v * 4 + 3] = __float2bfloat16(d.w);
      }
      uint4* dst = reinterpret_cast<uint4*>(&Bs[arow * 32 + acol]);
      dst[0] = tmp.u[0]; dst[1] = tmp.u[1];
    }
    __syncthreads();
    bf16x8 av[4], bv[4];
    #pragma unroll
    for (int mt = 0; mt < 4; mt++)
      av[mt] = *reinterpret_cast<const bf16x8*>(&As[(wm + mt * 16 + m16) * 32 + q * 8]);
    #pragma unroll
    for (int nt = 0; nt < 4; nt++)
      bv[nt] = *reinterpret_cast<const bf16x8*>(&Bs[(wn + nt * 16 + m16) * 32 + q * 8]);
    #pragma unroll
    for (int mt = 0; mt < 4; mt++)
      #pragma unroll
      for (int nt = 0; nt < 4; nt++)
        acc[mt][nt] = __builtin_amdgcn_mfma_f32_16x16x32_bf16(av[mt], bv[nt], acc[mt][nt], 0, 0, 0);
    __syncthreads();
  }
  #pragma unroll
  for (int mt = 0; mt < 4; mt++) {
    #pragma unroll
    for (int nt = 0; nt < 4; nt++) {
      #pragma unroll
      for (int r = 0; r < 4; r++) {
        int row = mb + wm + mt * 16 + q * 4 + r;
        int col = nb + wn + nt * 16 + m16;
        if (row < M && col < Nt) {
          float c = acc[mt][nt][r] + (bias ? bias[col] : 0.f);
          if (EPI == 1) c = geluf(c);
          C[(size_t)row * Nt + col] = c;
        }
      }
    }
  }
}

// ---------------- split-bf16 sim GEMM: C = xn @ xn^T at near-fp32 accuracy ----------------
__global__ __launch_bounds__(256)
void sim_split_kernel(const __hip_bfloat16* __restrict__ xh, const __hip_bfloat16* __restrict__ xl,
                      float* __restrict__ C) {
  __shared__ __align__(16) __hip_bfloat16 Ah[128 * 32];
  __shared__ __align__(16) __hip_bfloat16 Al[128 * 32];
  __shared__ __align__(16) __hip_bfloat16 Bh[128 * 32];
  __shared__ __align__(16) __hip_bfloat16 Bl[128 * 32];
  int mb = blockIdx.y * 128, nb = blockIdx.x * 128;
  int tid = threadIdx.x;
  int lane = tid & 63, wid = tid >> 6;
  int wm = (wid >> 1) * 64, wn = (wid & 1) * 64;
  int q = lane >> 4, m16 = lane & 15;
  int row = tid >> 1, halfk = (tid & 1) * 16;

  f32x4 acc[4][4];
  #pragma unroll
  for (int i = 0; i < 4; i++)
    #pragma unroll
    for (int j = 0; j < 4; j++) acc[i][j] = (f32x4){0.f, 0.f, 0.f, 0.f};

  uint4 z = {0u, 0u, 0u, 0u};
  for (int k0 = 0; k0 < 256; k0 += 32) {
    {
      int gr = mb + row; bool ok = gr < N_;
      const uint4* sh = reinterpret_cast<const uint4*>(xh + (size_t)gr * 256 + k0 + halfk);
      const uint4* sl = reinterpret_cast<const uint4*>(xl + (size_t)gr * 256 + k0 + halfk);
      uint4* dh = reinterpret_cast<uint4*>(&Ah[row * 32 + halfk]);
      uint4* dl = reinterpret_cast<uint4*>(&Al[row * 32 + halfk]);
      dh[0] = ok ? sh[0] : z; dh[1] = ok ? sh[1] : z;
      dl[0] = ok ? sl[0] : z; dl[1] = ok ? sl[1] : z;
    }
    {
      int gc = nb + row; bool ok = gc < N_;
      const uint4* sh = reinterpret_cast<const uint4*>(xh + (size_t)gc * 256 + k0 + halfk);
      const uint4* sl = reinterpret_cast<const uint4*>(xl + (size_t)gc * 256 + k0 + halfk);
      uint4* dh = reinterpret_cast<uint4*>(&Bh[row * 32 + halfk]);
      uint4* dl = reinterpret_cast<uint4*>(&Bl[row * 32 + halfk]);
      dh[0] = ok ? sh[0] : z; dh[1] = ok ? sh[1] : z;
      dl[0] = ok ? sl[0] : z; dl[1] = ok ? sl[1] : z;
    }
    __syncthreads();
    bf16x8 avh[4], avl[4], bvh[4], bvl[4];
    #pragma unroll
    for (int mt = 0; mt < 4; mt++) {
      avh[mt] = *reinterpret_cast<const bf16x8*>(&Ah[(wm + mt * 16 + m16) * 32 + q * 8]);
      avl[mt] = *reinterpret_cast<const bf16x8*>(&Al[(wm + mt * 16 + m16) * 32 + q * 8]);
    }
    #pragma unroll
    for (int nt = 0; nt < 4; nt++) {
      bvh[nt] = *reinterpret_cast<const bf16x8*>(&Bh[(wn + nt * 16 + m16) * 32 + q * 8]);
      bvl[nt] = *reinterpret_cast<const bf16x8*>(&Bl[(wn + nt * 16 + m16) * 32 + q * 8]);
    }
    #pragma unroll
    for (int mt = 0; mt < 4; mt++)
      #pragma unroll
      for (int nt = 0; nt < 4; nt++) {
        acc[mt][nt] = __builtin_amdgcn_mfma_f32_16x16x32_bf16(avh[mt], bvh[nt], acc[mt][nt], 0, 0, 0);
        acc[mt][nt] = __builtin_amdgcn_mfma_f32_16x16x32_bf16(avh[mt], bvl[nt], acc[mt][nt], 0, 0, 0);
        acc[mt][nt] = __builtin_amdgcn_mfma_f32_16x16x32_bf16(avl[mt], bvh[nt], acc[mt][nt], 0, 0, 0);
      }
    __syncthreads();
  }
  #pragma unroll
  for (int mt = 0; mt < 4; mt++)
    #pragma unroll
    for (int nt = 0; nt < 4; nt++)
      #pragma unroll
      for (int r = 0; r < 4; r++) {
        int rr = mb + wm + mt * 16 + q * 4 + r;
        int cc = nb + wn + nt * 16 + m16;
        if (rr < N_ && cc < N_) C[(size_t)rr * N_ + cc] = acc[mt][nt][r];
      }
}

// emb = LN(gelu(o) + emb)
__global__ __launch_bounds__(256)
void resid_gelu_ln_kernel(const float* __restrict__ o, float* __restrict__ emb,
                          const float* __restrict__ g, const float* __restrict__ b) {
  __shared__ float red[256];
  size_t row = blockIdx.x;
  int tid = threadIdx.x;
  float v = geluf(o[row * 256 + tid]) + emb[row * 256 + tid];
  float mean = block_sum_256(v, red) * (1.f / 256.f);
  float d = v - mean;
  float var = block_sum_256(d * d, red) * (1.f / 256.f);
  emb[row * 256 + tid] = d * rsqrtf(var + 1e-5f) * g[tid] + b[tid];
}

// ---------------- fused LN(q,k,v) + attention over F=16 tokens ----------------
__global__ __launch_bounds__(256)
void attn_ln_kernel(const float* __restrict__ qkv, float* __restrict__ out,
                    const float* __restrict__ gq, const float* __restrict__ bq,
                    const float* __restrict__ gk, const float* __restrict__ bk,
                    const float* __restrict__ gv, const float* __restrict__ bv) {
  __shared__ float tile[16][772];
  int n = blockIdx.x, tid = threadIdx.x;
  size_t base = (size_t)n * 16 * 768;
  for (int i4 = tid; i4 < 16 * 768 / 4; i4 += 256) {
    int idx = i4 * 4;
    int f = idx / 768, cc = idx % 768;
    *reinterpret_cast<float4*>(&tile[f][cc]) =
        *reinterpret_cast<const float4*>(qkv + base + idx);
  }
  __syncthreads();
  int lane = tid & 63, w = tid >> 6;
  for (int ii = 0; ii < 12; ii++) {
    int sl = w * 12 + ii;
    int s = sl >> 4, f = sl & 15;
    float* p = &tile[f][s * 256];
    float4 d = *reinterpret_cast<float4*>(p + lane * 4);
    float sum = d.x + d.y + d.z + d.w;
    #pragma unroll
    for (int m = 1; m < 64; m <<= 1) sum += __shfl_xor(sum, m, 64);
    float mean = sum * (1.f / 256.f);
    float e0 = d.x - mean, e1 = d.y - mean, e2 = d.z - mean, e3 = d.w - mean;
    float sq = e0 * e0 + e1 * e1 + e2 * e2 + e3 * e3;
    #pragma unroll
    for (int m = 1; m < 64; m <<= 1) sq += __shfl_xor(sq, m, 64);
    float inv = rsqrtf(sq * (1.f / 256.f) + 1e-5f);
    const float* g  = (s == 0) ? gq : (s == 1) ? gk : gv;
    const float* bb = (s == 0) ? bq : (s == 1) ? bk : bv;
    float4 gg = *reinterpret_cast<const float4*>(g + lane * 4);
    float4 bo = *reinterpret_cast<const float4*>(bb + lane * 4);
    d.x = e0 * inv * gg.x + bo.x;
    d.y = e1 * inv * gg.y + bo.y;
    d.z = e2 * inv * gg.z + bo.z;
    d.w = e3 * inv * gg.w + bo.w;
    *reinterpret_cast<float4*>(p + lane * 4) = d;
  }
  __syncthreads();
  int c = tid & 15, h = (tid >> 4) & 7, half = tid >> 7;
  const float scale = 0.17677669529663687f;  // 1/sqrt(32)
  float sc[16];
  float mx = -3e38f;
  #pragma unroll
  for (int s = 0; s < 16; s++) {
    float acc = 0.f;
    #pragma unroll
    for (int e = 0; e < 32; e++)
      acc += tile[c][h * 32 + e] * tile[s][256 + h * 32 + e];
    sc[s] = acc * scale;
    mx = fmaxf(mx, sc[s]);
  }
  float sum = 0.f;
  #pragma unroll
  for (int s = 0; s < 16; s++) { sc[s] = expf(sc[s] - mx); sum += sc[s]; }
  float inv = 1.f / sum;
  #pragma unroll
  for (int dd = 0; dd < 16; dd++) {
    int d = half * 16 + dd;
    float acc = 0.f;
    #pragma unroll
    for (int s = 0; s < 16; s++) acc += sc[s] * tile[s][512 + h * 32 + d];
    out[((size_t)n * 16 + c) * 256 + h * 32 + d] = acc * inv;
  }
}

// ---------------- feature importance ----------------
__global__ __launch_bounds__(256)
void rowdot_kernel(const float* __restrict__ A, const float* __restrict__ w,
                   const float* __restrict__ bscalar, float* __restrict__ out, int K) {
  __shared__ float red[256];
  int row = blockIdx.x, tid = threadIdx.x;
  float acc = 0.f;
  for (int d = tid; d < K; d += 256) acc += A[(size_t)row * K + d] * w[d];
  float s = block_sum_256(acc, red);
  if (tid == 0) out[row] = s + bscalar[0];
}

__global__ void fi_softmax_kernel(const float* __restrict__ w, float* __restrict__ fi) {
  int n = blockIdx.x * 256 + threadIdx.x;
  if (n >= N_) return;
  float mx = -3e38f;
  for (int f = 0; f < 16; f++) mx = fmaxf(mx, w[n * 16 + f]);
  float e[16], s = 0.f;
  for (int f = 0; f < 16; f++) { e[f] = expf(w[n * 16 + f] - mx); s += e[f]; }
  float inv = 1.f / s;
  for (int f = 0; f < 16; f++) fi[n * 16 + f] = e[f] * inv;
}

__global__ __launch_bounds__(256)
void node_kernel(const float* __restrict__ fi, const float* __restrict__ emb,
                 float* __restrict__ node) {
  int n = blockIdx.x, d = threadIdx.x;
  float acc = 0.f;
  for (int f = 0; f < 16; f++)
    acc += fi[n * 16 + f] * emb[((size_t)n * 16 + f) * 256 + d];
  node[(size_t)n * 256 + d] = acc;
}

// l2-normalize + split into bf16 hi/lo
__global__ __launch_bounds__(256)
void l2norm_split_kernel(const float* __restrict__ in, __hip_bfloat16* __restrict__ xh,
                         __hip_bfloat16* __restrict__ xl) {
  __shared__ float red[256];
  size_t row = blockIdx.x;
  int tid = threadIdx.x;
  float v = in[row * 256 + tid];
  float ss = block_sum_256(v * v, red);
  float y = v * rsqrtf(ss + 1e-12f);
  __hip_bfloat16 h = __float2bfloat16(y);
  xh[row * 256 + tid] = h;
  xl[row * 256 + tid] = __float2bfloat16(y - __bfloat162float(h));
}

// ---------------- top-k / bottom-k: register bitwise binary-search select ----------------
// Per row: each thread caches 24 fmap'd values; 32-level binary search on the
// threshold bits with popcount counting (no LDS histograms, no atomics in the
// hot loop). Exact lax.top_k set semantics (ties -> lowest index).
__global__ __launch_bounds__(256)
void topk_kernel(const float* __restrict__ sim, int* __restrict__ top,
                 int* __restrict__ bot) {
  __shared__ unsigned wsum[2][4];
  __shared__ unsigned short tie[1024];
  __shared__ unsigned s_out, s_tcnt;
  int i = blockIdx.x, tid = threadIdx.x;
  int lane = tid & 63, wid = tid >> 6;
  unsigned raw[24];
  unsigned validmask = 0;
  #pragma unroll
  for (int k = 0; k < 24; k++) {
    int j = tid + k * 256;
    bool ok = (j < N_) && (j != i);
    raw[k] = ok ? fmap(sim[(size_t)i * N_ + j]) : 0u;
    validmask |= (ok ? 1u : 0u) << k;
  }
  for (int pass = 0; pass < 2; pass++) {
    int* dst = pass ? bot : top;
    unsigned match = validmask;
    unsigned pref = 0;
    unsigned r = KK_;
    for (int bit = 31; bit >= 0; bit--) {
      unsigned bmask = 0;
      if (match) {
        #pragma unroll
        for (int k = 0; k < 24; k++) bmask |= ((raw[k] >> bit) & 1u) << k;
      }
      unsigned eff = pass ? (~bmask & 0x00ffffffu) : bmask;
      int cnt = __popc(match & eff);
      #pragma unroll
      for (int m = 1; m < 64; m <<= 1) cnt += __shfl_xor(cnt, m, 64);
      if (lane == 0) wsum[bit & 1][wid] = (unsigned)cnt;
      __syncthreads();
      unsigned total = wsum[bit & 1][0] + wsum[bit & 1][1] + wsum[bit & 1][2] + wsum[bit & 1][3];
      if (total >= r) { match &= eff; pref |= 1u << bit; }
      else            { r -= total; match &= ~eff; }
    }
    unsigned T = pref;
    if (tid == 0) { s_out = 0; s_tcnt = 0; }
    __syncthreads();
    #pragma unroll
    for (int k = 0; k < 24; k++) {
      if ((validmask >> k) & 1u) {
        unsigned v = pass ? ~raw[k] : raw[k];
        if (v > T) {
          unsigned p = atomicAdd(&s_out, 1u);
          dst[i * KK_ + p] = tid + k * 256;
        } else if (v == T) {
          unsigned q = atomicAdd(&s_tcnt, 1u);
          if (q < 1024u) tie[q] = (unsigned short)(tid + k * 256);
        }
      }
    }
    __syncthreads();
    int tcnt = (int)min(s_tcnt, 1024u);
    int basep = KK_ - (int)r;
    int last = -1;
    for (int t = 0; t < (int)r; t++) {
      unsigned best = 0xffffffffu;
      for (int idx = tid; idx < tcnt; idx += 256) {
        int j = (int)tie[idx];
        if (j > last && (unsigned)j < best) best = (unsigned)j;
      }
      #pragma unroll
      for (int m = 1; m < 64; m <<= 1) best = min(best, (unsigned)__shfl_xor((int)best, m, 64));
      if (lane == 0) wsum[t & 1][wid] = best;
      __syncthreads();
      best = min(min(wsum[t & 1][0], wsum[t & 1][1]), min(wsum[t & 1][2], wsum[t & 1][3]));
      last = (int)best;
      if (tid == 0) dst[i * KK_ + basep + t] = last;
    }
    __syncthreads();
  }
}

// ---------------- GAT ----------------
__global__ void gat_esed_kernel(const float* __restrict__ h, const float* __restrict__ asrc,
                                const float* __restrict__ adst,
                                float* __restrict__ es, float* __restrict__ ed) {
  int idx = blockIdx.x * 256 + threadIdx.x;
  if (idx >= N_ * H_) return;
  int hh = idx & 7;
  const float* hp = h + (size_t)(idx >> 3) * 256 + hh * 32;
  float a = 0.f, b = 0.f;
  for (int d = 0; d < 32; d++) {
    float hv = hp[d];
    a += hv * asrc[hh * 32 + d];
    b += hv * adst[hh * 32 + d];
  }
  es[idx] = a; ed[idx] = b;
}

__global__ void gat_init_kernel(unsigned* __restrict__ m_u, float* __restrict__ sbuf,
                                float* __restrict__ out) {
  int idx = blockIdx.x * 256 + threadIdx.x;
  if (idx < N_ * H_) { m_u[idx] = fmap(-1e9f); sbuf[idx] = 0.f; }
  if (idx < N_ * D_) out[idx] = 0.f;
}

__device__ __forceinline__ void edge_decode(int e, const int* nbr, int& src, int& tgt, bool& valid) {
  if (e < N_ * KK_) { src = e / KK_; tgt = nbr[e]; valid = (src != tgt); }
  else { src = tgt = e - N_ * KK_; valid = true; }
}

__global__ void gat_edge_max_kernel(const int* __restrict__ nbr, const float* __restrict__ es,
                                    const float* __restrict__ ed, unsigned* __restrict__ m_u) {
  int t = blockIdx.x * 256 + threadIdx.x;
  if (t >= E_ * H_) return;
  int e = t >> 3, hh = t & 7;
  int src, tgt; bool valid;
  edge_decode(e, nbr, src, tgt, valid);
  float ev = -1e9f;
  if (valid) {
    float xv = es[src * H_ + hh] + ed[tgt * H_ + hh];
    ev = xv > 0.f ? xv : 0.2f * xv;
  }
  atomicMax(&m_u[tgt * H_ + hh], fmap(ev));
}

__global__ void gat_edge_sum_kernel(const int* __restrict__ nbr, const float* __restrict__ es,
                                    const float* __restrict__ ed, const unsigned* __restrict__ m_u,
                                    float* __restrict__ sbuf, float* __restrict__ p) {
  int t = blockIdx.x * 256 + threadIdx.x;
  if (t >= E_ * H_) return;
  int e = t >> 3, hh = t & 7;
  int src, tgt; bool valid;
  edge_decode(e, nbr, src, tgt, valid);
  float pv = 0.f;
  if (valid) {
    float xv = es[src * H_ + hh] + ed[tgt * H_ + hh];
    float ev = xv > 0.f ? xv : 0.2f * xv;
    pv = expf(ev - funmap(m_u[tgt * H_ + hh]));
  }
  p[t] = pv;
  if (pv != 0.f) atomicAdd(&sbuf[tgt * H_ + hh], pv);
}

__global__ __launch_bounds__(256)
void gat_agg_kernel(const int* __restrict__ nbr, const float* __restrict__ p,
                    const float* __restrict__ sbuf, const float* __restrict__ h,
                    float* __restrict__ out) {
  long long t = (long long)blockIdx.x * 256 + threadIdx.x;
  if (t >= (long long)E_ * 256) return;
  int e = (int)(t >> 8), d = (int)(t & 255), hh = d >> 5;
  int src, tgt; bool valid;
  edge_decode(e, nbr, src, tgt, valid);
  float pv = p[e * H_ + hh];
  if (pv == 0.f) return;
  float alpha = pv / (sbuf[tgt * H_ + hh] + 1e-16f);
  atomicAdd(&out[(size_t)tgt * 256 + d], alpha * h[(size_t)src * 256 + d]);
}

__global__ void add_bias_kernel(float* __restrict__ out, const float* __restrict__ bias) {
  int idx = blockIdx.x * 256 + threadIdx.x;
  if (idx < N_ * D_) out[idx] += bias[idx & 255];
}

// ---------------- gating fuse + double LN ----------------
__global__ __launch_bounds__(256)
void fuse_kernel(const float* __restrict__ so, const float* __restrict__ to,
                 const float* __restrict__ bo, const float* __restrict__ impW,
                 const float* __restrict__ impb, const float* __restrict__ node,
                 const float* __restrict__ gag, const float* __restrict__ gab,
                 const float* __restrict__ fing, const float* __restrict__ finb,
                 float* __restrict__ outv) {
  __shared__ float red[256];
  size_t row = blockIdx.x;
  int tid = threadIdx.x;
  float s0 = so[row * 256 + tid];
  float t0 = to[row * 256 + tid];
  float b0 = bo[row * 256 + tid];
  float l0 = block_sum_256(s0 * impW[tid], red) + impb[0];
  float l1 = block_sum_256(t0 * impW[256 + tid], red) + impb[1];
  float l2 = block_sum_256(b0 * impW[512 + tid], red) + impb[2];
  float mx = fmaxf(l0, fmaxf(l1, l2));
  float e0 = expf(l0 - mx), e1 = expf(l1 - mx), e2 = expf(l2 - mx);
  float inv = 1.f / (e0 + e1 + e2);
  float fused = (e0 * s0 + e1 * t0 + e2 * b0) * inv;
  float v = geluf(fused) + node[row * 256 + tid];
  float mean = block_sum_256(v, red) * (1.f / 256.f);
  float d = v - mean;
  float var = block_sum_256(d * d, red) * (1.f / 256.f);
  float y = d * rsqrtf(var + 1e-5f) * gag[tid] + gab[tid];
  mean = block_sum_256(y, red) * (1.f / 256.f);
  d = y - mean;
  var = block_sum_256(d * d, red) * (1.f / 256.f);
  outv[row * 256 + tid] = d * rsqrtf(var + 1e-5f) * fing[tid] + finb[tid];
}

// ---------------- host launch ----------------
// Workspace (floats), peak 41,431,040 fl = 165.8 MB (< proven-safe 172 MB):
//   emb 0..24,576,000 | qkvbuf 24,576,000..33,792,000 | obuf 33,792,000..36,864,000
//   wbuf 36,864,000 | fibuf 36,960,000 | nodeb 37,056,000..38,592,000
//   xh (bf16) 38,592,000..39,360,000 | xl (bf16) 39,360,000..40,128,000
//   topi 40,128,000 | boti 40,320,000 | wtb 40,512,000..41,431,040
//   sim overlays 0..36,000,000; post-topk smalls overlay dead sim [0..12,528,000)
extern "C" void kernel_launch(void* const* d_in, const int* in_sizes, int n_in,
                              void* d_out, int out_size, void* d_ws, size_t ws_size,
                              hipStream_t stream) {
  const float* x        = (const float*)d_in[0];
  const float* gru_Wih  = (const float*)d_in[1];
  const float* gru_bih  = (const float*)d_in[2];
  const float* gru_bhh  = (const float*)d_in[3];
  const float* va_Wq    = (const float*)d_in[4];
  const float* va_bq    = (const float*)d_in[5];
  const float* va_Wk    = (const float*)d_in[6];
  const float* va_bk    = (const float*)d_in[7];
  const float* va_Wv    = (const float*)d_in[8];
  const float* va_bv    = (const float*)d_in[9];
  const float* va_lnq_g = (const float*)d_in[10];
  const float* va_lnq_b = (const float*)d_in[11];
  const float* va_lnk_g = (const float*)d_in[12];
  const float* va_lnk_b = (const float*)d_in[13];
  const float* va_lnv_g = (const float*)d_in[14];
  const float* va_lnv_b = (const float*)d_in[15];
  const float* va_Wo    = (const float*)d_in[16];
  const float* va_bo    = (const float*)d_in[17];
  const float* va_ln_g  = (const float*)d_in[18];
  const float* va_ln_b  = (const float*)d_in[19];
  const float* va_fi_W1 = (const float*)d_in[20];
  const float* va_fi_b1 = (const float*)d_in[21];
  const float* va_fi_W2 = (const float*)d_in[22];
  const float* va_fi_b2 = (const float*)d_in[23];
  const float* gat_W    = (const float*)d_in[24];
  const float* gat_asrc = (const float*)d_in[25];
  const float* gat_adst = (const float*)d_in[26];
  const float* gat_bias = (const float*)d_in[27];
  const float* imp_W    = (const float*)d_in[28];
  const float* imp_b    = (const float*)d_in[29];
  const float* ga_ln_g  = (const float*)d_in[30];
  const float* ga_ln_b  = (const float*)d_in[31];
  const float* fin_ln_g = (const float*)d_in[32];
  const float* fin_ln_b = (const float*)d_in[33];
  const float* pred_W1  = (const float*)d_in[34];
  const float* pred_b1  = (const float*)d_in[35];
  const float* pred_W2  = (const float*)d_in[36];
  const float* pred_b2  = (const float*)d_in[37];

  float* base   = (float*)d_ws;
  float* emb    = base;
  float* qkvbuf = base + 24576000;
  float* obuf   = base + 33792000;
  float* wbuf   = base + 36864000;
  float* fibuf  = base + 36960000;
  float* nodeb  = base + 37056000;
  __hip_bfloat16* xh = (__hip_bfloat16*)(base + 38592000);
  __hip_bfloat16* xl = (__hip_bfloat16*)(base + 39360000);
  int*   topi   = (int*)(base + 40128000);
  int*   boti   = (int*)(base + 40320000);
  float* wtb    = base + 40512000;
  float* simb   = base;
  // post-topk overlays:
  float* so     = base + 0;
  float* to     = base + 1536000;
  float* bo     = base + 3072000;
  float* hbuf   = base + 4608000;
  float* esb    = base + 6144000;
  float* edb    = base + 6192000;
  unsigned* mu  = (unsigned*)(base + 6240000);
  float* sb     = base + 6288000;
  float* pb     = base + 6336000;
  float* outv   = base + 7920000;
  float* hid    = base + 9456000;

  // wtb sub-offsets
  float* qkvt0  = wtb + 0;
  float* qkvt1  = wtb + 196608;
  float* wot0   = wtb + 393216;
  float* wot1   = wtb + 458752;
  float* fi1t   = wtb + 524288;
  float* gatt   = wtb + 589824;
  float* pred1t = wtb + 786432;
  float* qkvb   = wtb + 917504;

  // --- weight prep
  transpose_kernel<<<256, 256, 0, stream>>>(va_Wq,           qkvt0,          256);
  transpose_kernel<<<256, 256, 0, stream>>>(va_Wk,           qkvt0 + 65536,  256);
  transpose_kernel<<<256, 256, 0, stream>>>(va_Wv,           qkvt0 + 131072, 256);
  transpose_kernel<<<256, 256, 0, stream>>>(va_Wq + 65536,   qkvt1,          256);
  transpose_kernel<<<256, 256, 0, stream>>>(va_Wk + 65536,   qkvt1 + 65536,  256);
  transpose_kernel<<<256, 256, 0, stream>>>(va_Wv + 65536,   qkvt1 + 131072, 256);
  transpose_kernel<<<256, 256, 0, stream>>>(va_Wo,           wot0,           256);
  transpose_kernel<<<256, 256, 0, stream>>>(va_Wo + 65536,   wot1,           256);
  transpose_kernel<<<256, 256, 0, stream>>>(va_fi_W1 + (L_-1)*65536, fi1t,   256);
  transpose_kernel<<<256, 256, 0, stream>>>(gat_W,           gatt,           256);
  transpose_kernel<<<256, 256, 0, stream>>>(gat_W + 65536,   gatt + 65536,   256);
  transpose_kernel<<<256, 256, 0, stream>>>(gat_W + 131072,  gatt + 131072,  256);
  transpose_kernel<<<512, 256, 0, stream>>>(pred_W1,         pred1t,         512);
  biascat_kernel<<<dim3(3, 2), 256, 0, stream>>>(va_bq, va_bk, va_bv, qkvb);

  // --- TimeMixing GRU
  gru_kernel<<<dim3(94, 4, 16), 256, 0, stream>>>(x, gru_Wih, gru_bih, gru_bhh, emb);

  // --- Variable attention layers (fused qkv GEMM + fused LN+attn)
  for (int l = 0; l < L_; l++) {
    const float* qkvt = l ? qkvt1 : qkvt0;
    const float* wot  = l ? wot1  : wot0;
    for (int c = 0; c < NCHUNK_; c++) {
      float* embc = emb + (size_t)c * NC_ * F_ * D_;
      gemm_bt_bf16<0><<<dim3(6, 94), 256, 0, stream>>>(embc, qkvt, qkvb + l * 768,
                                                       qkvbuf, CR_, 256, 768);
      attn_ln_kernel<<<NC_, 256, 0, stream>>>(qkvbuf, obuf,
                                              va_lnq_g + l * 256, va_lnq_b + l * 256,
                                              va_lnk_g + l * 256, va_lnk_b + l * 256,
                                              va_lnv_g + l * 256, va_lnv_b + l * 256);
      gemm_bt_bf16<0><<<dim3(2, 94), 256, 0, stream>>>(obuf, wot, va_bo + l * 256,
                                                       qkvbuf, CR_, 256, 256);
      resid_gelu_ln_kernel<<<CR_, 256, 0, stream>>>(qkvbuf, embc, va_ln_g + l * 256, va_ln_b + l * 256);
    }
  }

  // --- feature importance
  for (int c = 0; c < NCHUNK_; c++) {
    float* embc = emb + (size_t)c * NC_ * F_ * D_;
    gemm_bt_bf16<1><<<dim3(2, 94), 256, 0, stream>>>(embc, fi1t, va_fi_b1 + (L_-1) * 256,
                                                     obuf, CR_, 256, 256);
    rowdot_kernel<<<CR_, 256, 0, stream>>>(obuf, va_fi_W2 + (L_-1) * 256, va_fi_b2 + (L_-1),
                                           wbuf + (size_t)c * CR_, 256);
  }
  fi_softmax_kernel<<<(N_ + 255) / 256, 256, 0, stream>>>(wbuf, fibuf);
  node_kernel<<<N_, 256, 0, stream>>>(fibuf, emb, nodeb);

  // --- cosine similarity (split-bf16, fp32-grade) + top/bottom-k
  l2norm_split_kernel<<<N_, 256, 0, stream>>>(nodeb, xh, xl);
  sim_split_kernel<<<dim3(47, 47), 256, 0, stream>>>(xh, xl, simb);
  topk_kernel<<<N_, 256, 0, stream>>>(simb, topi, boti);

  // --- self branch
  gemm_bt_bf16<0><<<dim3(2, 47), 256, 0, stream>>>(nodeb, gatt, gat_bias, so, N_, 256, 256);

  // --- top GAT
  gemm_bt_bf16<0><<<dim3(2, 47), 256, 0, stream>>>(nodeb, gatt + 65536, nullptr, hbuf, N_, 256, 256);
  gat_esed_kernel<<<(N_ * H_ + 255) / 256, 256, 0, stream>>>(hbuf, gat_asrc + 256, gat_adst + 256, esb, edb);
  gat_init_kernel<<<N_, 256, 0, stream>>>(mu, sb, to);
  gat_edge_max_kernel<<<(E_ * H_ + 255) / 256, 256, 0, stream>>>(topi, esb, edb, mu);
  gat_edge_sum_kernel<<<(E_ * H_ + 255) / 256, 256, 0, stream>>>(topi, esb, edb, mu, sb, pb);
  gat_agg_kernel<<<E_, 256, 0, stream>>>(topi, pb, sb, hbuf, to);
  add_bias_kernel<<<(N_ * D_ + 255) / 256, 256, 0, stream>>>(to, gat_bias + 256);

  // --- bottom GAT
  gemm_bt_bf16<0><<<dim3(2, 47), 256, 0, stream>>>(nodeb, gatt + 131072, nullptr, hbuf, N_, 256, 256);
  gat_esed_kernel<<<(N_ * H_ + 255) / 256, 256, 0, stream>>>(hbuf, gat_asrc + 512, gat_adst + 512, esb, edb);
  gat_init_kernel<<<N_, 256, 0, stream>>>(mu, sb, bo);
  gat_edge_max_kernel<<<(E_ * H_ + 255) / 256, 256, 0, stream>>>(boti, esb, edb, mu);
  gat_edge_sum_kernel<<<(E_ * H_ + 255) / 256, 256, 0, stream>>>(boti, esb, edb, mu, sb, pb);
  gat_agg_kernel<<<E_, 256, 0, stream>>>(boti, pb, sb, hbuf, bo);
  add_bias_kernel<<<(N_ * D_ + 255) / 256, 256, 0, stream>>>(bo, gat_bias + 512);

  // --- gating fuse + double LN
  fuse_kernel<<<N_, 256, 0, stream>>>(so, to, bo, imp_W, imp_b, nodeb,
                                      ga_ln_g, ga_ln_b, fin_ln_g, fin_ln_b, outv);

  // --- predictor
  gemm_bt_bf16<1><<<dim3(4, 47), 256, 0, stream>>>(outv, pred1t, pred_b1, hid, N_, 256, 512);
  rowdot_kernel<<<N_, 256, 0, stream>>>(hid, pred_W2, pred_b2, (float*)d_out, 512);
}

// Round 6
// 2871.506 us; speedup vs baseline: 2.0064x; 1.2136x over previous
//
#include <hip/hip_runtime.h>
#include <hip/hip_bf16.h>
#include <math.h>

#define N_  6000
#define F_  16
#define S_  64
#define D_  256
#define H_  8
#define KK_ 32
#define L_  2
#define DH_ 32
#define E_  (N_*KK_ + N_)   // 198000 edges
#define NF_ (N_*F_)         // 96000 token rows

typedef float f32x4 __attribute__((ext_vector_type(4)));
typedef float f32v4 __attribute__((ext_vector_type(4)));
typedef __bf16 bf16_t;
typedef bf16_t bf16x8 __attribute__((ext_vector_type(8)));

// ---------------- device helpers ----------------

__device__ __forceinline__ float geluf(float x) {
  return 0.5f * x * (1.0f + erff(x * 0.7071067811865476f));
}
__device__ __forceinline__ float sigmf(float x) {
  return 1.0f / (1.0f + expf(-x));
}
__device__ __forceinline__ float block_sum_256(float v, float* red) {
  int tid = threadIdx.x;
  red[tid] = v; __syncthreads();
  #pragma unroll
  for (int s = 128; s > 0; s >>= 1) {
    if (tid < s) red[tid] += red[tid + s];
    __syncthreads();
  }
  float r = red[0];
  __syncthreads();
  return r;
}
__device__ __forceinline__ unsigned fmap(float f) {
  unsigned u = __float_as_uint(f);
  return (u & 0x80000000u) ? ~u : (u | 0x80000000u);
}
__device__ __forceinline__ float funmap(unsigned u) {
  unsigned b = (u & 0x80000000u) ? (u ^ 0x80000000u) : ~u;
  return __uint_as_float(b);
}

// ---------------- weight prep ----------------
__global__ void transpose_kernel(const float* __restrict__ src, float* __restrict__ dst, int OUT) {
  int o = blockIdx.x, i = threadIdx.x;
  dst[(size_t)o * 256 + i] = src[(size_t)i * OUT + o];
}
__global__ void biascat_kernel(const float* __restrict__ bq, const float* __restrict__ bk,
                               const float* __restrict__ bv, float* __restrict__ dst) {
  int s = blockIdx.x, l = blockIdx.y, t = threadIdx.x;
  const float* p = (s == 0) ? bq : (s == 1) ? bk : bv;
  dst[l * 768 + s * 256 + t] = p[l * 256 + t];
}
__global__ void gatbias_kernel(const float* __restrict__ gb, float* __restrict__ b3) {
  int t = blockIdx.x * 256 + threadIdx.x;
  if (t < 768) b3[t] = (t < 256) ? gb[t] : 0.f;
}
// split GRU weights into bf16 hi/lo (once; reused by 94 row-blocks)
__global__ void gruw_split_kernel(const float* __restrict__ Wih,
                                  __hip_bfloat16* __restrict__ Wh,
                                  __hip_bfloat16* __restrict__ Wl) {
  size_t idx = (size_t)blockIdx.x * 256 + threadIdx.x;  // 16*768*64 = 786432
  float v = Wih[idx];
  __hip_bfloat16 h = __float2bfloat16(v);
  Wh[idx] = h;
  Wl[idx] = __float2bfloat16(v - __bfloat162float(h));
}

// ---------------- GRU: split-bf16 MFMA, fused gate epilogue ----------------
// grid (2, 94, 16): x=kb (128-col half of D), y=64-row block, z=feature
// Per block: accR/accZ/accN [64x128] via 3-chain split MFMA (hh+hl+lh), then
// emb[n,f,k] = (1-sigm(gz+bz))*tanh(gn+bin+sigm(gr+br)*bhn) directly.
__global__ __launch_bounds__(256)
void gru_mfma_kernel(const float* __restrict__ x,
                     const __hip_bfloat16* __restrict__ Wh,
                     const __hip_bfloat16* __restrict__ Wl,
                     const float* __restrict__ bih, const float* __restrict__ bhh,
                     float* __restrict__ emb) {
  __shared__ __align__(16) __hip_bfloat16 Ash[64 * 32];
  __shared__ __align__(16) __hip_bfloat16 Asl[64 * 32];
  __shared__ __align__(16) __hip_bfloat16 Bsh[384 * 32];
  __shared__ __align__(16) __hip_bfloat16 Bsl[384 * 32];
  int kb = blockIdx.x, rb = blockIdx.y, f = blockIdx.z;
  int tid = threadIdx.x;
  int lane = tid & 63, wid = tid >> 6;
  int wrow = (wid & 1) * 32, wcol = (wid >> 1) * 64;
  int q = lane >> 4, m16 = lane & 15;

  f32x4 aR[2][4], aZ[2][4], aN[2][4];
  #pragma unroll
  for (int i = 0; i < 2; i++)
    #pragma unroll
    for (int j = 0; j < 4; j++) {
      aR[i][j] = (f32x4){0.f,0.f,0.f,0.f};
      aZ[i][j] = (f32x4){0.f,0.f,0.f,0.f};
      aN[i][j] = (f32x4){0.f,0.f,0.f,0.f};
    }

  for (int k0 = 0; k0 < 64; k0 += 32) {
    // stage A (x rows, fp32 -> hi/lo bf16)
    {
      int r = tid >> 2, c0 = (tid & 3) * 8;
      int gn = rb * 64 + r;
      bool ok = gn < N_;
      const float* src = x + ((size_t)gn * F_ + f) * S_ + k0 + c0;
      #pragma unroll
      for (int v = 0; v < 2; v++) {
        f32v4 d = ok ? *reinterpret_cast<const f32v4*>(src + v * 4) : (f32v4){0.f,0.f,0.f,0.f};
        union { __hip_bfloat16 h[4]; uint2 u; } th, tl;
        th.h[0] = __float2bfloat16(d.x); tl.h[0] = __float2bfloat16(d.x - __bfloat162float(th.h[0]));
        th.h[1] = __float2bfloat16(d.y); tl.h[1] = __float2bfloat16(d.y - __bfloat162float(th.h[1]));
        th.h[2] = __float2bfloat16(d.z); tl.h[2] = __float2bfloat16(d.z - __bfloat162float(th.h[2]));
        th.h[3] = __float2bfloat16(d.w); tl.h[3] = __float2bfloat16(d.w - __bfloat162float(th.h[3]));
        *reinterpret_cast<uint2*>(&Ash[r * 32 + c0 + v * 4]) = th.u;
        *reinterpret_cast<uint2*>(&Asl[r * 32 + c0 + v * 4]) = tl.u;
      }
    }
    // stage B (pre-split bf16, straight copy): 384 rows (3 gates x 128 cols)
    #pragma unroll
    for (int i = 0; i < 2; i++) {
      int rid = tid + i * 256;
      if (rid < 384) {
        size_t roff = ((size_t)f * 768 + (rid >> 7) * 256 + kb * 128 + (rid & 127)) * S_ + k0;
        const uint4* sh = reinterpret_cast<const uint4*>(Wh + roff);
        const uint4* sl = reinterpret_cast<const uint4*>(Wl + roff);
        uint4* dh = reinterpret_cast<uint4*>(&Bsh[rid * 32]);
        uint4* dl = reinterpret_cast<uint4*>(&Bsl[rid * 32]);
        #pragma unroll
        for (int v = 0; v < 4; v++) { dh[v] = sh[v]; dl[v] = sl[v]; }
      }
    }
    __syncthreads();
    bf16x8 ah[2], al[2];
    #pragma unroll
    for (int mt = 0; mt < 2; mt++) {
      ah[mt] = *reinterpret_cast<const bf16x8*>(&Ash[(wrow + mt * 16 + m16) * 32 + q * 8]);
      al[mt] = *reinterpret_cast<const bf16x8*>(&Asl[(wrow + mt * 16 + m16) * 32 + q * 8]);
    }
    #pragma unroll
    for (int g = 0; g < 3; g++) {
      bf16x8 bh[4], bl[4];
      #pragma unroll
      for (int nt = 0; nt < 4; nt++) {
        int brow = g * 128 + wcol + nt * 16 + m16;
        bh[nt] = *reinterpret_cast<const bf16x8*>(&Bsh[brow * 32 + q * 8]);
        bl[nt] = *reinterpret_cast<const bf16x8*>(&Bsl[brow * 32 + q * 8]);
      }
      #pragma unroll
      for (int mt = 0; mt < 2; mt++)
        #pragma unroll
        for (int nt = 0; nt < 4; nt++) {
          f32x4 acc = (g == 0) ? aR[mt][nt] : (g == 1) ? aZ[mt][nt] : aN[mt][nt];
          acc = __builtin_amdgcn_mfma_f32_16x16x32_bf16(ah[mt], bh[nt], acc, 0, 0, 0);
          acc = __builtin_amdgcn_mfma_f32_16x16x32_bf16(ah[mt], bl[nt], acc, 0, 0, 0);
          acc = __builtin_amdgcn_mfma_f32_16x16x32_bf16(al[mt], bh[nt], acc, 0, 0, 0);
          if (g == 0) aR[mt][nt] = acc; else if (g == 1) aZ[mt][nt] = acc; else aN[mt][nt] = acc;
        }
    }
    __syncthreads();
  }
  // epilogue: gate math + store
  #pragma unroll
  for (int mt = 0; mt < 2; mt++)
    #pragma unroll
    for (int nt = 0; nt < 4; nt++) {
      int k = kb * 128 + wcol + nt * 16 + m16;
      float brc = bih[f * 768 + k]       + bhh[f * 768 + k];
      float bzc = bih[f * 768 + 256 + k] + bhh[f * 768 + 256 + k];
      float bni = bih[f * 768 + 512 + k];
      float bnh = bhh[f * 768 + 512 + k];
      #pragma unroll
      for (int r4 = 0; r4 < 4; r4++) {
        int gn = rb * 64 + wrow + mt * 16 + q * 4 + r4;
        if (gn < N_) {
          float rr = sigmf(aR[mt][nt][r4] + brc);
          float zz = sigmf(aZ[mt][nt][r4] + bzc);
          float nn = tanhf(aN[mt][nt][r4] + bni + rr * bnh);
          emb[((size_t)gn * F_ + f) * D_ + k] = (1.f - zz) * nn;
        }
      }
    }
}

// ---------------- bf16 MFMA GEMM (fp32 in/out) ----------------
template <int EPI>
__global__ __launch_bounds__(256)
void gemm_bt_bf16(const float* __restrict__ A, const float* __restrict__ Bt,
                  const float* __restrict__ bias, float* __restrict__ C,
                  int M, int K, int Nt) {
  __shared__ __align__(16) __hip_bfloat16 As[128 * 32];
  __shared__ __align__(16) __hip_bfloat16 Bs[128 * 32];
  int mb = blockIdx.y * 128, nb = blockIdx.x * 128;
  int tid = threadIdx.x;
  int lane = tid & 63, wid = tid >> 6;
  int wm = (wid >> 1) * 64, wn = (wid & 1) * 64;
  int q = lane >> 4, m16 = lane & 15;
  int arow = tid >> 1;
  int acol = (tid & 1) * 16;

  f32x4 acc[4][4];
  #pragma unroll
  for (int i = 0; i < 4; i++)
    #pragma unroll
    for (int j = 0; j < 4; j++) acc[i][j] = (f32x4){0.f, 0.f, 0.f, 0.f};

  for (int k0 = 0; k0 < K; k0 += 32) {
    {
      bool ok = (mb + arow) < M;
      const float* src = A + (size_t)(mb + arow) * K + k0 + acol;
      union { __hip_bfloat16 h[16]; uint4 u[2]; } tmp;
      #pragma unroll
      for (int v = 0; v < 4; v++) {
        f32v4 d = ok ? *reinterpret_cast<const f32v4*>(src + v * 4) : (f32v4){0.f,0.f,0.f,0.f};
        tmp.h[v * 4 + 0] = __float2bfloat16(d.x);
        tmp.h[v * 4 + 1] = __float2bfloat16(d.y);
        tmp.h[v * 4 + 2] = __float2bfloat16(d.z);
        tmp.h[v * 4 + 3] = __float2bfloat16(d.w);
      }
      uint4* dst = reinterpret_cast<uint4*>(&As[arow * 32 + acol]);
      dst[0] = tmp.u[0]; dst[1] = tmp.u[1];
    }
    {
      bool ok = (nb + arow) < Nt;
      const float* src = Bt + (size_t)(nb + arow) * K + k0 + acol;
      union { __hip_bfloat16 h[16]; uint4 u[2]; } tmp;
      #pragma unroll
      for (int v = 0; v < 4; v++) {
        f32v4 d = ok ? *reinterpret_cast<const f32v4*>(src + v * 4) : (f32v4){0.f,0.f,0.f,0.f};
        tmp.h[v * 4 + 0] = __float2bfloat16(d.x);
        tmp.h[v * 4 + 1] = __float2bfloat16(d.y);
        tmp.h[v * 4 + 2] = __float2bfloat16(d.z);
        tmp.h[v * 4 + 3] = __float2bfloat16(d.w);
      }
      uint4* dst = reinterpret_cast<uint4*>(&Bs[arow * 32 + acol]);
      dst[0] = tmp.u[0]; dst[1] = tmp.u[1];
    }
    __syncthreads();
    bf16x8 av[4], bv[4];
    #pragma unroll
    for (int mt = 0; mt < 4; mt++)
      av[mt] = *reinterpret_cast<const bf16x8*>(&As[(wm + mt * 16 + m16) * 32 + q * 8]);
    #pragma unroll
    for (int nt = 0; nt < 4; nt++)
      bv[nt] = *reinterpret_cast<const bf16x8*>(&Bs[(wn + nt * 16 + m16) * 32 + q * 8]);
    #pragma unroll
    for (int mt = 0; mt < 4; mt++)
      #pragma unroll
      for (int nt = 0; nt < 4; nt++)
        acc[mt][nt] = __builtin_amdgcn_mfma_f32_16x16x32_bf16(av[mt], bv[nt], acc[mt][nt], 0, 0, 0);
    __syncthreads();
  }
  #pragma unroll
  for (int mt = 0; mt < 4; mt++) {
    #pragma unroll
    for (int nt = 0; nt < 4; nt++) {
      #pragma unroll
      for (int r = 0; r < 4; r++) {
        int row = mb + wm + mt * 16 + q * 4 + r;
        int col = nb + wn + nt * 16 + m16;
        if (row < M && col < Nt) {
          float c = acc[mt][nt][r] + (bias ? bias[col] : 0.f);
          if (EPI == 1) c = geluf(c);
          C[(size_t)row * Nt + col] = c;
        }
      }
    }
  }
}

// ---------------- split-bf16 sim GEMM ----------------
__global__ __launch_bounds__(256)
void sim_split_kernel(const __hip_bfloat16* __restrict__ xh, const __hip_bfloat16* __restrict__ xl,
                      float* __restrict__ C) {
  __shared__ __align__(16) __hip_bfloat16 Ah[128 * 32];
  __shared__ __align__(16) __hip_bfloat16 Al[128 * 32];
  __shared__ __align__(16) __hip_bfloat16 Bh[128 * 32];
  __shared__ __align__(16) __hip_bfloat16 Bl[128 * 32];
  int mb = blockIdx.y * 128, nb = blockIdx.x * 128;
  int tid = threadIdx.x;
  int lane = tid & 63, wid = tid >> 6;
  int wm = (wid >> 1) * 64, wn = (wid & 1) * 64;
  int q = lane >> 4, m16 = lane & 15;
  int row = tid >> 1, halfk = (tid & 1) * 16;

  f32x4 acc[4][4];
  #pragma unroll
  for (int i = 0; i < 4; i++)
    #pragma unroll
    for (int j = 0; j < 4; j++) acc[i][j] = (f32x4){0.f, 0.f, 0.f, 0.f};

  uint4 z = {0u, 0u, 0u, 0u};
  for (int k0 = 0; k0 < 256; k0 += 32) {
    {
      int gr = mb + row; bool ok = gr < N_;
      const uint4* sh = reinterpret_cast<const uint4*>(xh + (size_t)gr * 256 + k0 + halfk);
      const uint4* sl = reinterpret_cast<const uint4*>(xl + (size_t)gr * 256 + k0 + halfk);
      uint4* dh = reinterpret_cast<uint4*>(&Ah[row * 32 + halfk]);
      uint4* dl = reinterpret_cast<uint4*>(&Al[row * 32 + halfk]);
      dh[0] = ok ? sh[0] : z; dh[1] = ok ? sh[1] : z;
      dl[0] = ok ? sl[0] : z; dl[1] = ok ? sl[1] : z;
    }
    {
      int gc = nb + row; bool ok = gc < N_;
      const uint4* sh = reinterpret_cast<const uint4*>(xh + (size_t)gc * 256 + k0 + halfk);
      const uint4* sl = reinterpret_cast<const uint4*>(xl + (size_t)gc * 256 + k0 + halfk);
      uint4* dh = reinterpret_cast<uint4*>(&Bh[row * 32 + halfk]);
      uint4* dl = reinterpret_cast<uint4*>(&Bl[row * 32 + halfk]);
      dh[0] = ok ? sh[0] : z; dh[1] = ok ? sh[1] : z;
      dl[0] = ok ? sl[0] : z; dl[1] = ok ? sl[1] : z;
    }
    __syncthreads();
    bf16x8 avh[4], avl[4], bvh[4], bvl[4];
    #pragma unroll
    for (int mt = 0; mt < 4; mt++) {
      avh[mt] = *reinterpret_cast<const bf16x8*>(&Ah[(wm + mt * 16 + m16) * 32 + q * 8]);
      avl[mt] = *reinterpret_cast<const bf16x8*>(&Al[(wm + mt * 16 + m16) * 32 + q * 8]);
    }
    #pragma unroll
    for (int nt = 0; nt < 4; nt++) {
      bvh[nt] = *reinterpret_cast<const bf16x8*>(&Bh[(wn + nt * 16 + m16) * 32 + q * 8]);
      bvl[nt] = *reinterpret_cast<const bf16x8*>(&Bl[(wn + nt * 16 + m16) * 32 + q * 8]);
    }
    #pragma unroll
    for (int mt = 0; mt < 4; mt++)
      #pragma unroll
      for (int nt = 0; nt < 4; nt++) {
        acc[mt][nt] = __builtin_amdgcn_mfma_f32_16x16x32_bf16(avh[mt], bvh[nt], acc[mt][nt], 0, 0, 0);
        acc[mt][nt] = __builtin_amdgcn_mfma_f32_16x16x32_bf16(avh[mt], bvl[nt], acc[mt][nt], 0, 0, 0);
        acc[mt][nt] = __builtin_amdgcn_mfma_f32_16x16x32_bf16(avl[mt], bvh[nt], acc[mt][nt], 0, 0, 0);
      }
    __syncthreads();
  }
  #pragma unroll
  for (int mt = 0; mt < 4; mt++)
    #pragma unroll
    for (int nt = 0; nt < 4; nt++)
      #pragma unroll
      for (int r = 0; r < 4; r++) {
        int rr = mb + wm + mt * 16 + q * 4 + r;
        int cc = nb + wn + nt * 16 + m16;
        if (rr < N_ && cc < N_) C[(size_t)rr * N_ + cc] = acc[mt][nt][r];
      }
}

// emb = LN(gelu(o) + emb)
__global__ __launch_bounds__(256)
void resid_gelu_ln_kernel(const float* __restrict__ o, float* __restrict__ emb,
                          const float* __restrict__ g, const float* __restrict__ b) {
  __shared__ float red[256];
  size_t row = blockIdx.x;
  int tid = threadIdx.x;
  float v = geluf(o[row * 256 + tid]) + emb[row * 256 + tid];
  float mean = block_sum_256(v, red) * (1.f / 256.f);
  float d = v - mean;
  float var = block_sum_256(d * d, red) * (1.f / 256.f);
  emb[row * 256 + tid] = d * rsqrtf(var + 1e-5f) * g[tid] + b[tid];
}

// ---------------- fused LN(q,k,v) + attention over F=16 tokens ----------------
__global__ __launch_bounds__(256)
void attn_ln_kernel(const float* __restrict__ qkv, float* __restrict__ out,
                    const float* __restrict__ gq, const float* __restrict__ bq,
                    const float* __restrict__ gk, const float* __restrict__ bk,
                    const float* __restrict__ gv, const float* __restrict__ bv) {
  __shared__ float tile[16][772];
  int n = blockIdx.x, tid = threadIdx.x;
  size_t base = (size_t)n * 16 * 768;
  for (int i4 = tid; i4 < 16 * 768 / 4; i4 += 256) {
    int idx = i4 * 4;
    int f = idx / 768, cc = idx % 768;
    *reinterpret_cast<float4*>(&tile[f][cc]) =
        *reinterpret_cast<const float4*>(qkv + base + idx);
  }
  __syncthreads();
  int lane = tid & 63, w = tid >> 6;
  for (int ii = 0; ii < 12; ii++) {
    int sl = w * 12 + ii;
    int s = sl >> 4, f = sl & 15;
    float* p = &tile[f][s * 256];
    float4 d = *reinterpret_cast<float4*>(p + lane * 4);
    float sum = d.x + d.y + d.z + d.w;
    #pragma unroll
    for (int m = 1; m < 64; m <<= 1) sum += __shfl_xor(sum, m, 64);
    float mean = sum * (1.f / 256.f);
    float e0 = d.x - mean, e1 = d.y - mean, e2 = d.z - mean, e3 = d.w - mean;
    float sq = e0 * e0 + e1 * e1 + e2 * e2 + e3 * e3;
    #pragma unroll
    for (int m = 1; m < 64; m <<= 1) sq += __shfl_xor(sq, m, 64);
    float inv = rsqrtf(sq * (1.f / 256.f) + 1e-5f);
    const float* g  = (s == 0) ? gq : (s == 1) ? gk : gv;
    const float* bb = (s == 0) ? bq : (s == 1) ? bk : bv;
    float4 gg = *reinterpret_cast<const float4*>(g + lane * 4);
    float4 bo = *reinterpret_cast<const float4*>(bb + lane * 4);
    d.x = e0 * inv * gg.x + bo.x;
    d.y = e1 * inv * gg.y + bo.y;
    d.z = e2 * inv * gg.z + bo.z;
    d.w = e3 * inv * gg.w + bo.w;
    *reinterpret_cast<float4*>(p + lane * 4) = d;
  }
  __syncthreads();
  int c = tid & 15, h = (tid >> 4) & 7, half = tid >> 7;
  const float scale = 0.17677669529663687f;  // 1/sqrt(32)
  float sc[16];
  float mx = -3e38f;
  #pragma unroll
  for (int s = 0; s < 16; s++) {
    float acc = 0.f;
    #pragma unroll
    for (int e = 0; e < 32; e++)
      acc += tile[c][h * 32 + e] * tile[s][256 + h * 32 + e];
    sc[s] = acc * scale;
    mx = fmaxf(mx, sc[s]);
  }
  float sum = 0.f;
  #pragma unroll
  for (int s = 0; s < 16; s++) { sc[s] = expf(sc[s] - mx); sum += sc[s]; }
  float inv = 1.f / sum;
  #pragma unroll
  for (int dd = 0; dd < 16; dd++) {
    int d = half * 16 + dd;
    float acc = 0.f;
    #pragma unroll
    for (int s = 0; s < 16; s++) acc += sc[s] * tile[s][512 + h * 32 + d];
    out[((size_t)n * 16 + c) * 256 + h * 32 + d] = acc * inv;
  }
}

// ---------------- feature importance ----------------
__global__ __launch_bounds__(256)
void rowdot_kernel(const float* __restrict__ A, const float* __restrict__ w,
                   const float* __restrict__ bscalar, float* __restrict__ out, int K) {
  __shared__ float red[256];
  int row = blockIdx.x, tid = threadIdx.x;
  float acc = 0.f;
  for (int d = tid; d < K; d += 256) acc += A[(size_t)row * K + d] * w[d];
  float s = block_sum_256(acc, red);
  if (tid == 0) out[row] = s + bscalar[0];
}

__global__ void fi_softmax_kernel(const float* __restrict__ w, float* __restrict__ fi) {
  int n = blockIdx.x * 256 + threadIdx.x;
  if (n >= N_) return;
  float mx = -3e38f;
  for (int f = 0; f < 16; f++) mx = fmaxf(mx, w[n * 16 + f]);
  float e[16], s = 0.f;
  for (int f = 0; f < 16; f++) { e[f] = expf(w[n * 16 + f] - mx); s += e[f]; }
  float inv = 1.f / s;
  for (int f = 0; f < 16; f++) fi[n * 16 + f] = e[f] * inv;
}

__global__ __launch_bounds__(256)
void node_kernel(const float* __restrict__ fi, const float* __restrict__ emb,
                 float* __restrict__ node) {
  int n = blockIdx.x, d = threadIdx.x;
  float acc = 0.f;
  for (int f = 0; f < 16; f++)
    acc += fi[n * 16 + f] * emb[((size_t)n * 16 + f) * 256 + d];
  node[(size_t)n * 256 + d] = acc;
}

// l2-normalize + split into bf16 hi/lo
__global__ __launch_bounds__(256)
void l2norm_split_kernel(const float* __restrict__ in, __hip_bfloat16* __restrict__ xh,
                         __hip_bfloat16* __restrict__ xl) {
  __shared__ float red[256];
  size_t row = blockIdx.x;
  int tid = threadIdx.x;
  float v = in[row * 256 + tid];
  float ss = block_sum_256(v * v, red);
  float y = v * rsqrtf(ss + 1e-12f);
  __hip_bfloat16 h = __float2bfloat16(y);
  xh[row * 256 + tid] = h;
  xl[row * 256 + tid] = __float2bfloat16(y - __bfloat162float(h));
}

// ---------------- top-k / bottom-k: register bitwise binary-search select ----------------
__global__ __launch_bounds__(256)
void topk_kernel(const float* __restrict__ sim, int* __restrict__ top,
                 int* __restrict__ bot) {
  __shared__ unsigned wsum[2][4];
  __shared__ unsigned short tie[1024];
  __shared__ unsigned s_out, s_tcnt;
  int i = blockIdx.x, tid = threadIdx.x;
  int lane = tid & 63, wid = tid >> 6;
  unsigned raw[24];
  unsigned validmask = 0;
  #pragma unroll
  for (int k = 0; k < 24; k++) {
    int j = tid + k * 256;
    bool ok = (j < N_) && (j != i);
    raw[k] = ok ? fmap(sim[(size_t)i * N_ + j]) : 0u;
    validmask |= (ok ? 1u : 0u) << k;
  }
  for (int pass = 0; pass < 2; pass++) {
    int* dst = pass ? bot : top;
    unsigned match = validmask;
    unsigned pref = 0;
    unsigned r = KK_;
    for (int bit = 31; bit >= 0; bit--) {
      unsigned bmask = 0;
      if (match) {
        #pragma unroll
        for (int k = 0; k < 24; k++) bmask |= ((raw[k] >> bit) & 1u) << k;
      }
      unsigned eff = pass ? (~bmask & 0x00ffffffu) : bmask;
      int cnt = __popc(match & eff);
      #pragma unroll
      for (int m = 1; m < 64; m <<= 1) cnt += __shfl_xor(cnt, m, 64);
      if (lane == 0) wsum[bit & 1][wid] = (unsigned)cnt;
      __syncthreads();
      unsigned total = wsum[bit & 1][0] + wsum[bit & 1][1] + wsum[bit & 1][2] + wsum[bit & 1][3];
      if (total >= r) { match &= eff; pref |= 1u << bit; }
      else            { r -= total; match &= ~eff; }
    }
    unsigned T = pref;
    if (tid == 0) { s_out = 0; s_tcnt = 0; }
    __syncthreads();
    #pragma unroll
    for (int k = 0; k < 24; k++) {
      if ((validmask >> k) & 1u) {
        unsigned v = pass ? ~raw[k] : raw[k];
        if (v > T) {
          unsigned p = atomicAdd(&s_out, 1u);
          dst[i * KK_ + p] = tid + k * 256;
        } else if (v == T) {
          unsigned q = atomicAdd(&s_tcnt, 1u);
          if (q < 1024u) tie[q] = (unsigned short)(tid + k * 256);
        }
      }
    }
    __syncthreads();
    int tcnt = (int)min(s_tcnt, 1024u);
    int basep = KK_ - (int)r;
    int last = -1;
    for (int t = 0; t < (int)r; t++) {
      unsigned best = 0xffffffffu;
      for (int idx = tid; idx < tcnt; idx += 256) {
        int j = (int)tie[idx];
        if (j > last && (unsigned)j < best) best = (unsigned)j;
      }
      #pragma unroll
      for (int m = 1; m < 64; m <<= 1) best = min(best, (unsigned)__shfl_xor((int)best, m, 64));
      if (lane == 0) wsum[t & 1][wid] = best;
      __syncthreads();
      best = min(min(wsum[t & 1][0], wsum[t & 1][1]), min(wsum[t & 1][2], wsum[t & 1][3]));
      last = (int)best;
      if (tid == 0) dst[i * KK_ + basep + t] = last;
    }
    __syncthreads();
  }
}

// ---------------- GAT ----------------
__global__ void gat_esed_kernel(const float* __restrict__ h, const float* __restrict__ asrc,
                                const float* __restrict__ adst,
                                float* __restrict__ es, float* __restrict__ ed, int ld) {
  int idx = blockIdx.x * 256 + threadIdx.x;
  if (idx >= N_ * H_) return;
  int hh = idx & 7;
  const float* hp = h + (size_t)(idx >> 3) * ld + hh * 32;
  float a = 0.f, b = 0.f;
  for (int d = 0; d < 32; d++) {
    float hv = hp[d];
    a += hv * asrc[hh * 32 + d];
    b += hv * adst[hh * 32 + d];
  }
  es[idx] = a; ed[idx] = b;
}

__global__ void gat_init_kernel(unsigned* __restrict__ m_u, float* __restrict__ sbuf,
                                float* __restrict__ out) {
  int idx = blockIdx.x * 256 + threadIdx.x;
  if (idx < N_ * H_) { m_u[idx] = fmap(-1e9f); sbuf[idx] = 0.f; }
  if (idx < N_ * D_) out[idx] = 0.f;
}

__device__ __forceinline__ void edge_decode(int e, const int* nbr, int& src, int& tgt, bool& valid) {
  if (e < N_ * KK_) { src = e / KK_; tgt = nbr[e]; valid = (src != tgt); }
  else { src = tgt = e - N_ * KK_; valid = true; }
}

__global__ void gat_edge_max_kernel(const int* __restrict__ nbr, const float* __restrict__ es,
                                    const float* __restrict__ ed, unsigned* __restrict__ m_u) {
  int t = blockIdx.x * 256 + threadIdx.x;
  if (t >= E_ * H_) return;
  int e = t >> 3, hh = t & 7;
  int src, tgt; bool valid;
  edge_decode(e, nbr, src, tgt, valid);
  float ev = -1e9f;
  if (valid) {
    float xv = es[src * H_ + hh] + ed[tgt * H_ + hh];
    ev = xv > 0.f ? xv : 0.2f * xv;
  }
  atomicMax(&m_u[tgt * H_ + hh], fmap(ev));
}

__global__ void gat_edge_sum_kernel(const int* __restrict__ nbr, const float* __restrict__ es,
                                    const float* __restrict__ ed, const unsigned* __restrict__ m_u,
                                    float* __restrict__ sbuf, float* __restrict__ p) {
  int t = blockIdx.x * 256 + threadIdx.x;
  if (t >= E_ * H_) return;
  int e = t >> 3, hh = t & 7;
  int src, tgt; bool valid;
  edge_decode(e, nbr, src, tgt, valid);
  float pv = 0.f;
  if (valid) {
    float xv = es[src * H_ + hh] + ed[tgt * H_ + hh];
    float ev = xv > 0.f ? xv : 0.2f * xv;
    pv = expf(ev - funmap(m_u[tgt * H_ + hh]));
  }
  p[t] = pv;
  if (pv != 0.f) atomicAdd(&sbuf[tgt * H_ + hh], pv);
}

__global__ __launch_bounds__(256)
void gat_agg_kernel(const int* __restrict__ nbr, const float* __restrict__ p,
                    const float* __restrict__ sbuf, const float* __restrict__ h,
                    float* __restrict__ out, int ld) {
  long long t = (long long)blockIdx.x * 256 + threadIdx.x;
  if (t >= (long long)E_ * 256) return;
  int e = (int)(t >> 8), d = (int)(t & 255), hh = d >> 5;
  int src, tgt; bool valid;
  edge_decode(e, nbr, src, tgt, valid);
  float pv = p[e * H_ + hh];
  if (pv == 0.f) return;
  float alpha = pv / (sbuf[tgt * H_ + hh] + 1e-16f);
  atomicAdd(&out[(size_t)tgt * 256 + d], alpha * h[(size_t)src * ld + d]);
}

__global__ void add_bias_kernel(float* __restrict__ out, const float* __restrict__ bias) {
  int idx = blockIdx.x * 256 + threadIdx.x;
  if (idx < N_ * D_) out[idx] += bias[idx & 255];
}

// ---------------- gating fuse + double LN ----------------
__global__ __launch_bounds__(256)
void fuse_kernel(const float* __restrict__ so, const float* __restrict__ to,
                 const float* __restrict__ bo, const float* __restrict__ impW,
                 const float* __restrict__ impb, const float* __restrict__ node,
                 const float* __restrict__ gag, const float* __restrict__ gab,
                 const float* __restrict__ fing, const float* __restrict__ finb,
                 float* __restrict__ outv, int ldso) {
  __shared__ float red[256];
  size_t row = blockIdx.x;
  int tid = threadIdx.x;
  float s0 = so[row * ldso + tid];
  float t0 = to[row * 256 + tid];
  float b0 = bo[row * 256 + tid];
  float l0 = block_sum_256(s0 * impW[tid], red) + impb[0];
  float l1 = block_sum_256(t0 * impW[256 + tid], red) + impb[1];
  float l2 = block_sum_256(b0 * impW[512 + tid], red) + impb[2];
  float mx = fmaxf(l0, fmaxf(l1, l2));
  float e0 = expf(l0 - mx), e1 = expf(l1 - mx), e2 = expf(l2 - mx);
  float inv = 1.f / (e0 + e1 + e2);
  float fused = (e0 * s0 + e1 * t0 + e2 * b0) * inv;
  float v = geluf(fused) + node[row * 256 + tid];
  float mean = block_sum_256(v, red) * (1.f / 256.f);
  float d = v - mean;
  float var = block_sum_256(d * d, red) * (1.f / 256.f);
  float y = d * rsqrtf(var + 1e-5f) * gag[tid] + gab[tid];
  mean = block_sum_256(y, red) * (1.f / 256.f);
  d = y - mean;
  var = block_sum_256(d * d, red) * (1.f / 256.f);
  outv[row * 256 + tid] = d * rsqrtf(var + 1e-5f) * fing[tid] + finb[tid];
}

// ---------------- host launch ----------------
// Workspace (floats): emb at 0 (24,576,000), then qkvbuf [CR,768], obuf [CR,256],
// then smalls (wbuf/fibuf/nodeb/xh/xl/topi/boti/wtb ~5.35M). NC chosen from ws_size:
//   NC=750  -> peak 42.2M fl (168.9 MB, proven-safe)
//   NC=1500 -> 54.5M | NC=3000 -> 79.1M | NC=6000 -> 128.2M
// sim overlays [0..36M) (emb/qkv dead); post-topk buffers overlay dead sim.
extern "C" void kernel_launch(void* const* d_in, const int* in_sizes, int n_in,
                              void* d_out, int out_size, void* d_ws, size_t ws_size,
                              hipStream_t stream) {
  const float* x        = (const float*)d_in[0];
  const float* gru_Wih  = (const float*)d_in[1];
  const float* gru_bih  = (const float*)d_in[2];
  const float* gru_bhh  = (const float*)d_in[3];
  const float* va_Wq    = (const float*)d_in[4];
  const float* va_bq    = (const float*)d_in[5];
  const float* va_Wk    = (const float*)d_in[6];
  const float* va_bk    = (const float*)d_in[7];
  const float* va_Wv    = (const float*)d_in[8];
  const float* va_bv    = (const float*)d_in[9];
  const float* va_lnq_g = (const float*)d_in[10];
  const float* va_lnq_b = (const float*)d_in[11];
  const float* va_lnk_g = (const float*)d_in[12];
  const float* va_lnk_b = (const float*)d_in[13];
  const float* va_lnv_g = (const float*)d_in[14];
  const float* va_lnv_b = (const float*)d_in[15];
  const float* va_Wo    = (const float*)d_in[16];
  const float* va_bo    = (const float*)d_in[17];
  const float* va_ln_g  = (const float*)d_in[18];
  const float* va_ln_b  = (const float*)d_in[19];
  const float* va_fi_W1 = (const float*)d_in[20];
  const float* va_fi_b1 = (const float*)d_in[21];
  const float* va_fi_W2 = (const float*)d_in[22];
  const float* va_fi_b2 = (const float*)d_in[23];
  const float* gat_W    = (const float*)d_in[24];
  const float* gat_asrc = (const float*)d_in[25];
  const float* gat_adst = (const float*)d_in[26];
  const float* gat_bias = (const float*)d_in[27];
  const float* imp_W    = (const float*)d_in[28];
  const float* imp_b    = (const float*)d_in[29];
  const float* ga_ln_g  = (const float*)d_in[30];
  const float* ga_ln_b  = (const float*)d_in[31];
  const float* fin_ln_g = (const float*)d_in[32];
  const float* fin_ln_b = (const float*)d_in[33];
  const float* pred_W1  = (const float*)d_in[34];
  const float* pred_b1  = (const float*)d_in[35];
  const float* pred_W2  = (const float*)d_in[36];
  const float* pred_b2  = (const float*)d_in[37];

  // pick chunk size from available workspace (constant per harness -> deterministic)
  size_t wsfl = ws_size / 4;
  int NCv;
  if      (wsfl >= 128300000) NCv = 6000;
  else if (wsfl >=  79100000) NCv = 3000;
  else if (wsfl >=  54600000) NCv = 1500;
  else                        NCv = 750;
  int NCH = N_ / NCv;
  int CRv = NCv * F_;
  int gyCR = (CRv + 127) / 128;

  float* base   = (float*)d_ws;
  float* emb    = base;
  size_t qkvoff = 24576000;
  float* qkvbuf = base + qkvoff;
  float* obuf   = qkvbuf + (size_t)CRv * 768;
  float* smalls = obuf + (size_t)CRv * 256;
  float* wbuf   = smalls;
  float* fibuf  = smalls + 96000;
  float* nodeb  = smalls + 192000;
  __hip_bfloat16* xh = (__hip_bfloat16*)(smalls + 1728000);
  __hip_bfloat16* xl = (__hip_bfloat16*)(smalls + 2496000);
  int*   topi   = (int*)(smalls + 3264000);
  int*   boti   = (int*)(smalls + 3456000);
  float* wtb    = smalls + 3648000;
  float* simb   = base;
  // post-topk overlays (dead sim region):
  float* gout   = base + 0;          // [N,768] self|top-h|bot-h
  float* to     = base + 4608000;
  float* bo     = base + 6144000;
  float* esb    = base + 7680000;
  float* edb    = base + 7728000;
  unsigned* mu  = (unsigned*)(base + 7776000);
  float* sb     = base + 7824000;
  float* pb     = base + 7872000;
  float* outv   = base + 9456000;
  float* hid    = base + 10992000;

  // wtb sub-offsets
  float* qkvt0  = wtb + 0;
  float* qkvt1  = wtb + 196608;
  float* wot0   = wtb + 393216;
  float* wot1   = wtb + 458752;
  float* fi1t   = wtb + 524288;
  float* gatt   = wtb + 589824;
  float* pred1t = wtb + 786432;
  float* qkvb   = wtb + 917504;
  float* b3     = wtb + 919040;
  __hip_bfloat16* gwh = (__hip_bfloat16*)(wtb + 919808);   // [16*768*64] bf16 hi
  __hip_bfloat16* gwl = (__hip_bfloat16*)(wtb + 1313024);  // lo

  // --- weight prep
  transpose_kernel<<<256, 256, 0, stream>>>(va_Wq,           qkvt0,          256);
  transpose_kernel<<<256, 256, 0, stream>>>(va_Wk,           qkvt0 + 65536,  256);
  transpose_kernel<<<256, 256, 0, stream>>>(va_Wv,           qkvt0 + 131072, 256);
  transpose_kernel<<<256, 256, 0, stream>>>(va_Wq + 65536,   qkvt1,          256);
  transpose_kernel<<<256, 256, 0, stream>>>(va_Wk + 65536,   qkvt1 + 65536,  256);
  transpose_kernel<<<256, 256, 0, stream>>>(va_Wv + 65536,   qkvt1 + 131072, 256);
  transpose_kernel<<<256, 256, 0, stream>>>(va_Wo,           wot0,           256);
  transpose_kernel<<<256, 256, 0, stream>>>(va_Wo + 65536,   wot1,           256);
  transpose_kernel<<<256, 256, 0, stream>>>(va_fi_W1 + (L_-1)*65536, fi1t,   256);
  transpose_kernel<<<256, 256, 0, stream>>>(gat_W,           gatt,           256);
  transpose_kernel<<<256, 256, 0, stream>>>(gat_W + 65536,   gatt + 65536,   256);
  transpose_kernel<<<256, 256, 0, stream>>>(gat_W + 131072,  gatt + 131072,  256);
  transpose_kernel<<<512, 256, 0, stream>>>(pred_W1,         pred1t,         512);
  biascat_kernel<<<dim3(3, 2), 256, 0, stream>>>(va_bq, va_bk, va_bv, qkvb);
  gatbias_kernel<<<3, 256, 0, stream>>>(gat_bias, b3);
  gruw_split_kernel<<<3072, 256, 0, stream>>>(gru_Wih, gwh, gwl);

  // --- TimeMixing GRU (split-bf16 MFMA + fused gates)
  gru_mfma_kernel<<<dim3(2, 94, 16), 256, 0, stream>>>(x, gwh, gwl, gru_bih, gru_bhh, emb);

  // --- Variable attention layers (fused qkv GEMM + fused LN+attn)
  for (int l = 0; l < L_; l++) {
    const float* qkvt = l ? qkvt1 : qkvt0;
    const float* wot  = l ? wot1  : wot0;
    for (int c = 0; c < NCH; c++) {
      float* embc = emb + (size_t)c * NCv * F_ * D_;
      gemm_bt_bf16<0><<<dim3(6, gyCR), 256, 0, stream>>>(embc, qkvt, qkvb + l * 768,
                                                         qkvbuf, CRv, 256, 768);
      attn_ln_kernel<<<NCv, 256, 0, stream>>>(qkvbuf, obuf,
                                              va_lnq_g + l * 256, va_lnq_b + l * 256,
                                              va_lnk_g + l * 256, va_lnk_b + l * 256,
                                              va_lnv_g + l * 256, va_lnv_b + l * 256);
      gemm_bt_bf16<0><<<dim3(2, gyCR), 256, 0, stream>>>(obuf, wot, va_bo + l * 256,
                                                         qkvbuf, CRv, 256, 256);
      resid_gelu_ln_kernel<<<CRv, 256, 0, stream>>>(qkvbuf, embc, va_ln_g + l * 256, va_ln_b + l * 256);
    }
  }

  // --- feature importance
  for (int c = 0; c < NCH; c++) {
    float* embc = emb + (size_t)c * NCv * F_ * D_;
    gemm_bt_bf16<1><<<dim3(2, gyCR), 256, 0, stream>>>(embc, fi1t, va_fi_b1 + (L_-1) * 256,
                                                       obuf, CRv, 256, 256);
    rowdot_kernel<<<CRv, 256, 0, stream>>>(obuf, va_fi_W2 + (L_-1) * 256, va_fi_b2 + (L_-1),
                                           wbuf + (size_t)c * CRv, 256);
  }
  fi_softmax_kernel<<<(N_ + 255) / 256, 256, 0, stream>>>(wbuf, fibuf);
  node_kernel<<<N_, 256, 0, stream>>>(fibuf, emb, nodeb);

  // --- cosine similarity (split-bf16, fp32-grade) + top/bottom-k
  l2norm_split_kernel<<<N_, 256, 0, stream>>>(nodeb, xh, xl);
  sim_split_kernel<<<dim3(47, 47), 256, 0, stream>>>(xh, xl, simb);
  topk_kernel<<<N_, 256, 0, stream>>>(simb, topi, boti);

  // --- merged self/top/bot projection GEMM -> gout [N,768]
  gemm_bt_bf16<0><<<dim3(6, 47), 256, 0, stream>>>(nodeb, gatt, b3, gout, N_, 256, 768);

  // --- top GAT (h = gout+256, stride 768)
  gat_esed_kernel<<<(N_ * H_ + 255) / 256, 256, 0, stream>>>(gout + 256, gat_asrc + 256, gat_adst + 256, esb, edb, 768);
  gat_init_kernel<<<N_, 256, 0, stream>>>(mu, sb, to);
  gat_edge_max_kernel<<<(E_ * H_ + 255) / 256, 256, 0, stream>>>(topi, esb, edb, mu);
  gat_edge_sum_kernel<<<(E_ * H_ + 255) / 256, 256, 0, stream>>>(topi, esb, edb, mu, sb, pb);
  gat_agg_kernel<<<E_, 256, 0, stream>>>(topi, pb, sb, gout + 256, to, 768);
  add_bias_kernel<<<(N_ * D_ + 255) / 256, 256, 0, stream>>>(to, gat_bias + 256);

  // --- bottom GAT (h = gout+512)
  gat_esed_kernel<<<(N_ * H_ + 255) / 256, 256, 0, stream>>>(gout + 512, gat_asrc + 512, gat_adst + 512, esb, edb, 768);
  gat_init_kernel<<<N_, 256, 0, stream>>>(mu, sb, bo);
  gat_edge_max_kernel<<<(E_ * H_ + 255) / 256, 256, 0, stream>>>(boti, esb, edb, mu);
  gat_edge_sum_kernel<<<(E_ * H_ + 255) / 256, 256, 0, stream>>>(boti, esb, edb, mu, sb, pb);
  gat_agg_kernel<<<E_, 256, 0, stream>>>(boti, pb, sb, gout + 512, bo, 768);
  add_bias_kernel<<<(N_ * D_ + 255) / 256, 256, 0, stream>>>(bo, gat_bias + 512);

  // --- gating fuse + double LN (so = gout cols 0-255, stride 768)
  fuse_kernel<<<N_, 256, 0, stream>>>(gout, to, bo, imp_W, imp_b, nodeb,
                                      ga_ln_g, ga_ln_b, fin_ln_g, fin_ln_b, outv, 768);

  // --- predictor
  gemm_bt_bf16<1><<<dim3(4, 47), 256, 0, stream>>>(outv, pred1t, pred_b1, hid, N_, 256, 512);
  rowdot_kernel<<<N_, 256, 0, stream>>>(hid, pred_W2, pred_b2, (float*)d_out, 512);
}